// Round 4
// baseline (6134.849 us; speedup 1.0000x reference)
//
#include <hip/hip_runtime.h>
#include <hip/hip_bf16.h>

#define DEV static __device__ __forceinline__

typedef short short8 __attribute__((ext_vector_type(8)));
typedef float f32x4 __attribute__((ext_vector_type(4)));

#define NB 512
#define SL 256
#define ED 300
#define HD 200

DEV short f2b(float f){ __hip_bfloat16 h = __float2bfloat16(f); short s; __builtin_memcpy(&s,&h,2); return s; }

// ---------------- generic MLP GEMM: C(M x 200) = act(A(M x K) @ W(K x 200) + b) ----------------
// A_MODE 0: A = Asrc (bf16 ws) row-major (M x K)
// A_MODE 1: A[row][k] = emb[idx[row]][k]              (K=300, emb fp32)
// A_MODE 2: A[row][k] = k<300 ? emb[idx[row]][k] : Xtra[row][k-300]   (K=600, Xtra bf16 ws)
// DO_SUM: multiply rows by mask(pos<len[b]) and reduce over rows into Vout[b][col] (atomic)
template<int A_MODE, int KDIM, bool DO_SUM>
__global__ __launch_bounds__(256) void mlp_gemm(
    const short* __restrict__ Asrc, const float* __restrict__ emb,
    const int* __restrict__ idx, const short* __restrict__ Xtra,
    const float* __restrict__ Wb, const float* __restrict__ bias,
    short* __restrict__ Cout, const int* __restrict__ lenArr,
    float* __restrict__ Vout)
{
  constexpr int N = HD;               // 200
  constexpr int NT = 13, BNP = 208, PAD = 40;
  __shared__ __align__(16) short As[64*PAD];
  __shared__ __align__(16) short Bs[BNP*PAD];
  const int tid = threadIdx.x, lane = tid&63, w = tid>>6, quad = lane>>4;
  const int row0 = blockIdx.x*64;
  f32x4 acc[NT];
  #pragma unroll
  for (int t=0;t<NT;t++) acc[t] = (f32x4){0.f,0.f,0.f,0.f};
  constexpr int NKS = (KDIM+31)/32;
  for (int ks=0;ks<NKS;ks++){
    const int k0 = ks*32;
    #pragma unroll
    for (int it=0;it<8;it++){
      int p = it*256+tid, r = p>>5, kk = p&31, k = k0+kk;
      short v = 0;
      if (k < KDIM){
        if constexpr (A_MODE==0) v = Asrc[(size_t)(row0+r)*KDIM + k];
        else if constexpr (A_MODE==1) v = f2b(emb[(size_t)idx[row0+r]*ED + k]);
        else v = (k < ED) ? f2b(emb[(size_t)idx[row0+r]*ED + k])
                          : Xtra[(size_t)(row0+r)*ED + (k-ED)];
      }
      As[r*PAD+kk] = v;
    }
    for (int it=0;it<26;it++){          // 26*256 = 32*208
      int p = it*256+tid, kk = p/BNP, n = p-kk*BNP, k = k0+kk;
      short v = 0;
      if (k < KDIM && n < N) v = f2b(Wb[(size_t)k*N + n]);
      Bs[n*PAD+kk] = v;
    }
    __syncthreads();
    short8 a = *(const short8*)&As[(w*16+(lane&15))*PAD + quad*8];
    #pragma unroll
    for (int t=0;t<NT;t++){
      short8 bb = *(const short8*)&Bs[(t*16+(lane&15))*PAD + quad*8];
      acc[t] = __builtin_amdgcn_mfma_f32_16x16x32_bf16(a, bb, acc[t], 0,0,0);
    }
    __syncthreads();
  }
  if constexpr (!DO_SUM){
    #pragma unroll
    for (int t=0;t<NT;t++){
      int col = t*16+(lane&15);
      if (col < N){
        float bv = bias[col];
        #pragma unroll
        for (int r=0;r<4;r++){
          int rl = w*16+quad*4+r;
          float v = fmaxf(acc[t][r] + bv, 0.f);
          Cout[(size_t)(row0+rl)*N + col] = f2b(v);
        }
      }
    }
  } else {
    int b = row0 >> 8;
    int lenv = lenArr[b];
    int posBase = (row0 & 255) + w*16 + quad*4;
    #pragma unroll
    for (int t=0;t<NT;t++){
      int col = t*16+(lane&15);
      float bv = (col < N) ? bias[col] : 0.f;
      float s = 0.f;
      #pragma unroll
      for (int r=0;r<4;r++){
        float v = fmaxf(acc[t][r] + bv, 0.f);
        if (posBase + r < lenv) s += v;
      }
      s += __shfl_xor(s,16);
      s += __shfl_xor(s,32);
      if (quad==0 && col<N) atomicAdd(&Vout[b*N+col], s);
    }
  }
}

// ---------------- scores: e[b][i][j] = sum_k h1[b][i][k]*h2[b][j][k] (fp32 out) ----------------
__global__ __launch_bounds__(256) void scores_gemm(
    const short* __restrict__ h1, const short* __restrict__ h2, float* __restrict__ e)
{
  constexpr int PAD = 40;
  __shared__ __align__(16) short As[64*PAD];
  __shared__ __align__(16) short Bs[64*PAD];
  const int b = blockIdx.z;
  const int i0 = blockIdx.x*64, j0 = blockIdx.y*64;
  const int tid = threadIdx.x, lane = tid&63, w = tid>>6, quad = lane>>4;
  const short* A  = h1 + (size_t)b*SL*HD;
  const short* Bm = h2 + (size_t)b*SL*HD;
  f32x4 acc[4];
  #pragma unroll
  for (int t=0;t<4;t++) acc[t] = (f32x4){0.f,0.f,0.f,0.f};
  for (int ks=0;ks<7;ks++){
    int k0 = ks*32;
    #pragma unroll
    for (int it=0;it<8;it++){
      int p = it*256+tid, r = p>>5, kk = p&31, k = k0+kk;
      As[r*PAD+kk] = (k<HD) ? A[(size_t)(i0+r)*HD + k] : (short)0;
      Bs[r*PAD+kk] = (k<HD) ? Bm[(size_t)(j0+r)*HD + k] : (short)0;
    }
    __syncthreads();
    short8 a = *(const short8*)&As[(w*16+(lane&15))*PAD + quad*8];
    #pragma unroll
    for (int t=0;t<4;t++){
      short8 bb = *(const short8*)&Bs[(t*16+(lane&15))*PAD + quad*8];
      acc[t] = __builtin_amdgcn_mfma_f32_16x16x32_bf16(a, bb, acc[t], 0,0,0);
    }
    __syncthreads();
  }
  #pragma unroll
  for (int t=0;t<4;t++){
    int j = j0 + t*16 + (lane&15);
    #pragma unroll
    for (int r=0;r<4;r++){
      int i = i0 + w*16 + quad*4 + r;
      e[(size_t)b*SL*SL + (size_t)i*SL + j] = acc[t][r];
    }
  }
}

// ---------------- row/col maxes over e ----------------
__global__ __launch_bounds__(256) void colrow_max(
    const float* __restrict__ e, float* __restrict__ R, float* __restrict__ Cm)
{
  const int b = blockIdx.x, t = threadIdx.x;
  const float* eb = e + (size_t)b*SL*SL;
  float cm = -INFINITY;
  for (int i=0;i<SL;i++) cm = fmaxf(cm, eb[(size_t)i*SL + t]);   // col max over i
  Cm[b*SL+t] = cm;
  float rm = -INFINITY;
  for (int j=0;j<SL;j++) rm = fmaxf(rm, eb[(size_t)t*SL + j]);   // row max over j
  R[b*SL+t] = rm;
}

// ---------------- alpha weights, NORMALIZED + masked, stored transposed:
// Pa[b][j][i] = exp(min(e[i][j]-R[j],85))*[i<l1] / sum_i(same)
__global__ __launch_bounds__(256) void softmax_alpha(
    const float* __restrict__ e, const float* __restrict__ R,
    const int* __restrict__ len1, short* __restrict__ Pa)
{
  const int b = blockIdx.x, j = threadIdx.x;
  const float* eb = e + (size_t)b*SL*SL;
  const float rm = R[b*SL+j];
  const int l1 = len1[b];
  float s = 0.f;
  for (int i=0;i<l1;i++) s += __expf(fminf(eb[(size_t)i*SL+j]-rm, 85.f));
  const float inv = (s > 0.f) ? 1.f/s : 0.f;
  short* prow = Pa + (size_t)b*SL*SL + (size_t)j*SL;
  for (int i=0;i<SL;i++){
    float p = (i < l1) ? __expf(fminf(eb[(size_t)i*SL+j]-rm, 85.f))*inv : 0.f;
    prow[i] = f2b(p);
  }
}

// ---------------- beta weights, NORMALIZED + masked:
// Pb[b][i][j] = exp(min(e[i][j]-Cm[i],85))*[j<l2] / sum_j(same)
__global__ __launch_bounds__(256) void softmax_beta(
    const float* __restrict__ e, const float* __restrict__ Cm,
    const int* __restrict__ len2, short* __restrict__ Pb)
{
  const int b = blockIdx.x, i = threadIdx.x;
  const float* er = e + (size_t)b*SL*SL + (size_t)i*SL;
  const float cm = Cm[b*SL+i];
  const int l2 = len2[b];
  float s = 0.f;
  for (int j=0;j<l2;j++) s += __expf(fminf(er[j]-cm, 85.f));
  const float inv = (s > 0.f) ? 1.f/s : 0.f;
  short* prow = Pb + (size_t)b*SL*SL + (size_t)i*SL;
  for (int j=0;j<SL;j++){
    float p = (j < l2) ? __expf(fminf(er[j]-cm, 85.f))*inv : 0.f;
    prow[j] = f2b(p);
  }
}

// ---------------- Out[b][m][0:300] = mask(m) * sum_k P[b][m][k] * emb[idx[b][k]][:] ----------------
__global__ __launch_bounds__(256) void pe_gemm(
    const short* __restrict__ P,
    const int* __restrict__ lenArr, const int* __restrict__ idx,
    const float* __restrict__ emb, short* __restrict__ Out)
{
  constexpr int NT = 19, BNP = 304, PAD = 40;
  __shared__ __align__(16) short As[64*PAD];
  __shared__ __align__(16) short Bs[BNP*PAD];
  const int b = blockIdx.y, row0 = blockIdx.x*64;
  const int tid = threadIdx.x, lane = tid&63, w = tid>>6, quad = lane>>4;
  const short* Pb_ = P + (size_t)b*SL*SL;
  const int* ib = idx + b*SL;
  f32x4 acc[NT];
  #pragma unroll
  for (int t=0;t<NT;t++) acc[t] = (f32x4){0.f,0.f,0.f,0.f};
  for (int ks=0;ks<8;ks++){
    const int k0 = ks*32;
    #pragma unroll
    for (int it=0;it<8;it++){
      int p = it*256+tid, r = p>>5, kk = p&31;
      As[r*PAD+kk] = Pb_[(size_t)(row0+r)*SL + k0+kk];
    }
    for (int it=0;it<38;it++){           // 38*256 = 32*304
      int p = it*256+tid, kk = p/BNP, n = p-kk*BNP;
      short v = 0;
      if (n < ED) v = f2b(emb[(size_t)ib[k0+kk]*ED + n]);
      Bs[n*PAD+kk] = v;
    }
    __syncthreads();
    short8 a = *(const short8*)&As[(w*16+(lane&15))*PAD + quad*8];
    #pragma unroll
    for (int t=0;t<NT;t++){
      short8 bb = *(const short8*)&Bs[(t*16+(lane&15))*PAD + quad*8];
      acc[t] = __builtin_amdgcn_mfma_f32_16x16x32_bf16(a, bb, acc[t], 0,0,0);
    }
    __syncthreads();
  }
  const int lenv = lenArr[b];
  #pragma unroll
  for (int t=0;t<NT;t++){
    int col = t*16+(lane&15);
    if (col < ED){
      #pragma unroll
      for (int r=0;r<4;r++){
        int pos = row0 + w*16 + quad*4 + r;
        float sc = (pos < lenv) ? 1.f : 0.f;
        Out[((size_t)b*SL+pos)*ED + col] = f2b(acc[t][r]*sc);
      }
    }
  }
}

// ---------------- aggregate: out[b][0:2] (all fp32) ----------------
__global__ __launch_bounds__(256) void aggregate(
    const float* __restrict__ v1, const float* __restrict__ v2,
    const float* __restrict__ W1g, const float* __restrict__ b1g,
    const float* __restrict__ W2g, const float* __restrict__ b2g,
    float* __restrict__ out)
{
  __shared__ float z[2*HD];
  __shared__ float a[HD];
  const int b = blockIdx.x, t = threadIdx.x;
  if (t < HD){ z[t] = v1[b*HD+t]; z[HD+t] = v2[b*HD+t]; }
  __syncthreads();
  if (t < HD){
    float acc = b1g[t];
    for (int k=0;k<2*HD;k++) acc += z[k]*W1g[(size_t)k*HD+t];
    a[t] = fmaxf(acc, 0.f);
  }
  __syncthreads();
  if (t < 2){
    float acc = b2g[t];
    for (int k=0;k<HD;k++) acc += a[k]*W2g[k*2+t];
    out[b*2+t] = acc;
  }
}

extern "C" void kernel_launch(void* const* d_in, const int* in_sizes, int n_in,
                              void* d_out, int out_size, void* d_ws, size_t ws_size,
                              hipStream_t stream) {
  const float* emb = (const float*)d_in[0];
  const float* W1a = (const float*)d_in[1];  const float* b1a = (const float*)d_in[2];
  const float* W2a = (const float*)d_in[3];  const float* b2a = (const float*)d_in[4];
  const float* W1c = (const float*)d_in[5];  const float* b1c = (const float*)d_in[6];
  const float* W2c = (const float*)d_in[7];  const float* b2c = (const float*)d_in[8];
  const float* W1g = (const float*)d_in[9];  const float* b1g = (const float*)d_in[10];
  const float* W2g = (const float*)d_in[11]; const float* b2g = (const float*)d_in[12];
  const int* s1 = (const int*)d_in[13];
  const int* s2 = (const int*)d_in[14];
  const int* len1 = (const int*)d_in[15];
  const int* len2 = (const int*)d_in[16];
  float* out = (float*)d_out;
  char* W = (char*)d_ws;

  // ---- adaptive batch chunking: distinct (non-overlaid) per-chunk buffers ----
  // per-batch bytes: T/h1/h2 102400 ea (bf16), e 262144 (fp32), Pa/Pb 131072 ea (bf16),
  //                  al/be 153600 ea (bf16), R/Cm 1024 ea  => 1,140,736 B/batch
  // fixed: v1,v2 = 2*409,600 B (fp32)
  const size_t FIXED = 2ull*409600;
  const size_t PERB  = 1140736ull;
  int nbc = NB;                       // largest pow2 divisor of 512 that fits
  while (nbc > 1 && FIXED + (size_t)nbc*PERB > ws_size) nbc >>= 1;

  float* v1 = (float*)(W);
  float* v2 = (float*)(W + 409600);
  char* C0 = W + FIXED;
  const size_t nb = (size_t)nbc;
  short* T  = (short*)(C0);
  short* h1 = (short*)(C0 + nb*102400);
  short* h2 = (short*)(C0 + nb*204800);
  float* e  = (float*)(C0 + nb*307200);
  short* Pa = (short*)(C0 + nb*569344);
  short* Pb = (short*)(C0 + nb*700416);
  short* al = (short*)(C0 + nb*831488);
  short* be = (short*)(C0 + nb*985088);
  float* R  = (float*)(C0 + nb*1138688);
  float* Cm = (float*)(C0 + nb*1139712);

  const dim3 blk(256);
  const dim3 gM(nbc*4);               // (nbc*256 rows)/64
  hipMemsetAsync(v1, 0, 2ull*NB*HD*sizeof(float), stream);

  const int chunks = NB / nbc;
  for (int c = 0; c < chunks; c++){
    const int b0 = c * nbc;
    const int* s1c = s1 + (size_t)b0*SL;
    const int* s2c = s2 + (size_t)b0*SL;
    const int* l1c = len1 + b0;
    const int* l2c = len2 + b0;

    // attend MLP: h = relu(relu(e @ W1a + b1a) @ W2a + b2a)
    mlp_gemm<1,300,false><<<gM,blk,0,stream>>>(nullptr, emb, s1c, nullptr, W1a, b1a, T,  nullptr, nullptr);
    mlp_gemm<0,200,false><<<gM,blk,0,stream>>>(T,       emb, nullptr, nullptr, W2a, b2a, h1, nullptr, nullptr);
    mlp_gemm<1,300,false><<<gM,blk,0,stream>>>(nullptr, emb, s2c, nullptr, W1a, b1a, T,  nullptr, nullptr);
    mlp_gemm<0,200,false><<<gM,blk,0,stream>>>(T,       emb, nullptr, nullptr, W2a, b2a, h2, nullptr, nullptr);
    // scores + maxes + normalized weights
    scores_gemm<<<dim3(4,4,nbc),blk,0,stream>>>(h1, h2, e);
    colrow_max<<<dim3(nbc),blk,0,stream>>>(e, R, Cm);
    softmax_alpha<<<dim3(nbc),blk,0,stream>>>(e, R, l1c, Pa);
    softmax_beta <<<dim3(nbc),blk,0,stream>>>(e, Cm, l2c, Pb);
    // alphas[b][j] = sum_i Pa[j][i]*e1[i]  (rows masked by len2)
    // betas[b][i]  = sum_j Pb[i][j]*e2[j]  (rows masked by len1)
    pe_gemm<<<dim3(4,nbc),blk,0,stream>>>(Pa, l2c, s1c, emb, al);
    pe_gemm<<<dim3(4,nbc),blk,0,stream>>>(Pb, l1c, s2c, emb, be);
    // compare side1: concat(e1, betas) -> v1
    mlp_gemm<2,600,false><<<gM,blk,0,stream>>>(nullptr, emb, s1c, be, W1c, b1c, T, nullptr, nullptr);
    mlp_gemm<0,200,true ><<<gM,blk,0,stream>>>(T, emb, nullptr, nullptr, W2c, b2c, nullptr, l1c, v1 + (size_t)b0*HD);
    // compare side2: concat(e2, alphas) -> v2
    mlp_gemm<2,600,false><<<gM,blk,0,stream>>>(nullptr, emb, s2c, al, W1c, b1c, T, nullptr, nullptr);
    mlp_gemm<0,200,true ><<<gM,blk,0,stream>>>(T, emb, nullptr, nullptr, W2c, b2c, nullptr, l2c, v2 + (size_t)b0*HD);
  }
  // aggregate over full batch
  aggregate<<<dim3(NB),blk,0,stream>>>(v1, v2, W1g, b1g, W2g, b2g, out);
}

// Round 5
// 2710.432 us; speedup vs baseline: 2.2634x; 2.2634x over previous
//
#include <hip/hip_runtime.h>
#include <hip/hip_bf16.h>

#define DEV static __device__ __forceinline__

typedef short short8 __attribute__((ext_vector_type(8)));
typedef float f32x4 __attribute__((ext_vector_type(4)));

#define NB 512
#define SL 256
#define ED 300
#define HD 200
#define EP 320   // padded embed / concat-half / alpha-beta stride
#define HP 224   // padded hidden stride (200 -> 224)
#define TSP 232  // LDS layer-1 output tile stride
#define PAD 40

DEV short f2b(float f){ __hip_bfloat16 h = __float2bfloat16(f); short s; __builtin_memcpy(&s,&h,2); return s; }

// ---------- one-time conversions ----------
__global__ __launch_bounds__(256) void conv_emb(const float* __restrict__ src, short* __restrict__ dst){
  size_t g = (size_t)blockIdx.x*256 + threadIdx.x;
  if (g >= (size_t)50000*EP) return;
  int row = (int)(g/EP), k = (int)(g%EP);
  dst[g] = (k<ED) ? f2b(src[(size_t)row*ED + k]) : (short)0;
}
// Wt[n][k] (208 x KP) <- W[k][n] (Kreal x 200), zero padded
__global__ __launch_bounds__(256) void convT_plain(const float* __restrict__ W, short* __restrict__ Wt,
                                                   int Kreal, int KP){
  int g = blockIdx.x*256 + threadIdx.x;
  if (g >= 208*KP) return;
  int n = g/KP, k = g%KP;
  float v = (n<HD && k<Kreal) ? W[(size_t)k*HD + n] : 0.f;
  Wt[g] = f2b(v);
}
// W1c (600 x 200) -> Wt 208 x 640 with halves at k<320 (src 0..299) and k>=320 (src 300..599)
__global__ __launch_bounds__(256) void convT_split(const float* __restrict__ W, short* __restrict__ Wt){
  int g = blockIdx.x*256 + threadIdx.x;
  if (g >= 208*640) return;
  int n = g/640, k = g%640;
  int half = (k>=EP);
  int kk = k - half*EP;
  float v = (n<HD && kk<ED) ? W[(size_t)(half*ED+kk)*HD + n] : 0.f;
  Wt[g] = f2b(v);
}

// ---------- fused 2-layer MLP, both sides in one launch ----------
// AMODE 1: A = embb[idx[row]] (KP1=320);  AMODE 2: A = [embb[idx[row]] (320) | Xtra[row] (320)] (KP1=640)
// layer1: relu(A@W1t^T + b1) -> Ts (LDS);  layer2: relu(Ts@W2t^T + b2) -> Out (stride HP) or masked row-sum -> V
template<int KP1, int AMODE, bool DO_SUM>
__global__ __launch_bounds__(256) void mlp2(
    const short* __restrict__ embb,
    const int* __restrict__ idxA, const int* __restrict__ idxB,
    const short* __restrict__ XtraA, const short* __restrict__ XtraB,
    const short* __restrict__ W1t, const float* __restrict__ b1,
    const short* __restrict__ W2t, const float* __restrict__ b2,
    short* __restrict__ OutA, short* __restrict__ OutB,
    const int* __restrict__ lenA, const int* __restrict__ lenB,
    float* __restrict__ VA, float* __restrict__ VB)
{
  __shared__ __align__(16) short As[64*PAD];
  __shared__ __align__(16) short Bs[208*PAD];
  __shared__ __align__(16) short Ts[64*TSP];
  __shared__ int IdxS[64];
  const int tid=threadIdx.x, lane=tid&63, w=tid>>6, quad=lane>>4, ln=lane&15;
  const int half = gridDim.x>>1;
  const int side = (blockIdx.x >= half) ? 1 : 0;
  const int row0 = (blockIdx.x - side*half)*64;
  const int* idx = side ? idxB : idxA;
  const short* Xtra = side ? XtraB : XtraA;
  if (tid < 64) IdxS[tid] = idx[row0+tid];
  if (tid < 128){ int r=tid>>1, c=tid&1;
    short8 z = {0,0,0,0,0,0,0,0};
    *(short8*)&Ts[r*TSP + 208 + c*8] = z; }
  __syncthreads();

  f32x4 acc[13];
  #pragma unroll
  for (int t=0;t<13;t++) acc[t]=(f32x4){0.f,0.f,0.f,0.f};
  const int r_ = tid>>2, c_ = tid&3;

  // ---- layer 1 ----
  for (int ks=0; ks<KP1/32; ks++){
    const int k0 = ks*32;
    short8 av;
    if constexpr (AMODE==1){
      av = *(const short8*)&embb[(size_t)IdxS[r_]*EP + k0 + c_*8];
    } else {
      if (k0 < EP) av = *(const short8*)&embb[(size_t)IdxS[r_]*EP + k0 + c_*8];
      else         av = *(const short8*)&Xtra[(size_t)(row0+r_)*EP + (k0-EP) + c_*8];
    }
    *(short8*)&As[r_*PAD + c_*8] = av;
    #pragma unroll
    for (int it=0; it<4; it++){
      int p = it*256+tid, n = p>>2, cc = p&3;
      if (n < 208)
        *(short8*)&Bs[n*PAD + cc*8] = *(const short8*)&W1t[(size_t)n*KP1 + k0 + cc*8];
    }
    __syncthreads();
    short8 a = *(const short8*)&As[(w*16+ln)*PAD + quad*8];
    #pragma unroll
    for (int t=0;t<13;t++){
      short8 bb = *(const short8*)&Bs[(t*16+ln)*PAD + quad*8];
      acc[t] = __builtin_amdgcn_mfma_f32_16x16x32_bf16(a, bb, acc[t], 0,0,0);
    }
    __syncthreads();
  }
  // layer-1 epilogue -> Ts
  #pragma unroll
  for (int t=0;t<13;t++){
    int col = t*16+ln;
    float bv = (col<HD) ? b1[col] : 0.f;
    #pragma unroll
    for (int r=0;r<4;r++){
      int rl = w*16+quad*4+r;
      float v = (col<HD) ? fmaxf(acc[t][r]+bv, 0.f) : 0.f;
      Ts[rl*TSP + col] = f2b(v);
    }
    acc[t]=(f32x4){0.f,0.f,0.f,0.f};
  }
  // ---- layer 2 (K=224) ----
  for (int ks=0; ks<7; ks++){
    const int k0 = ks*32;
    #pragma unroll
    for (int it=0; it<4; it++){
      int p = it*256+tid, n = p>>2, cc = p&3;
      if (n < 208)
        *(short8*)&Bs[n*PAD + cc*8] = *(const short8*)&W2t[(size_t)n*HP + k0 + cc*8];
    }
    __syncthreads();
    short8 a = *(const short8*)&Ts[(w*16+ln)*TSP + k0 + quad*8];
    #pragma unroll
    for (int t=0;t<13;t++){
      short8 bb = *(const short8*)&Bs[(t*16+ln)*PAD + quad*8];
      acc[t] = __builtin_amdgcn_mfma_f32_16x16x32_bf16(a, bb, acc[t], 0,0,0);
    }
    __syncthreads();
  }
  if constexpr (!DO_SUM){
    short* Out = side ? OutB : OutA;
    #pragma unroll
    for (int t=0;t<13;t++){
      int col = t*16+ln;
      float bv = (col<HD) ? b2[col] : 0.f;
      #pragma unroll
      for (int r=0;r<4;r++){
        int rl = w*16+quad*4+r;
        float v = (col<HD) ? fmaxf(acc[t][r]+bv, 0.f) : 0.f;
        Out[(size_t)(row0+rl)*HP + col] = f2b(v);
      }
    }
    if (tid < 128){ int r=tid>>1, c=tid&1;
      short8 z = {0,0,0,0,0,0,0,0};
      *(short8*)&Out[(size_t)(row0+r)*HP + 208 + c*8] = z; }
  } else {
    const int* lenArr = side ? lenB : lenA;
    float* V = side ? VB : VA;
    const int b = row0>>8;
    const int lenv = lenArr[b];
    const int posBase = (row0&255) + w*16 + quad*4;
    #pragma unroll
    for (int t=0;t<13;t++){
      int col = t*16+ln;
      float bv = (col<HD) ? b2[col] : 0.f;
      float s = 0.f;
      #pragma unroll
      for (int r=0;r<4;r++){
        float v = fmaxf(acc[t][r]+bv, 0.f);
        if (posBase + r < lenv) s += v;
      }
      s += __shfl_xor(s,16);
      s += __shfl_xor(s,32);
      if (quad==0 && col<HD) atomicAdd(&V[b*HD+col], s);
    }
  }
}

// ---------- scores: e[b][i][j] = sum_k h1[b][i][k]*h2[b][j][k] ----------
__global__ __launch_bounds__(256) void scores_gemm(
    const short* __restrict__ h1, const short* __restrict__ h2, float* __restrict__ e)
{
  __shared__ __align__(16) short As[64*PAD];
  __shared__ __align__(16) short Bs[64*PAD];
  const int b = blockIdx.z;
  const int i0 = blockIdx.x*64, j0 = blockIdx.y*64;
  const int tid=threadIdx.x, lane=tid&63, w=tid>>6, quad=lane>>4, ln=lane&15;
  const int r_ = tid>>2, c_ = tid&3;
  f32x4 acc[4];
  #pragma unroll
  for (int t=0;t<4;t++) acc[t]=(f32x4){0.f,0.f,0.f,0.f};
  for (int ks=0; ks<7; ks++){
    const int k0 = ks*32;
    *(short8*)&As[r_*PAD + c_*8] = *(const short8*)&h1[((size_t)b*SL + i0 + r_)*HP + k0 + c_*8];
    *(short8*)&Bs[r_*PAD + c_*8] = *(const short8*)&h2[((size_t)b*SL + j0 + r_)*HP + k0 + c_*8];
    __syncthreads();
    short8 a = *(const short8*)&As[(w*16+ln)*PAD + quad*8];
    #pragma unroll
    for (int t=0;t<4;t++){
      short8 bb = *(const short8*)&Bs[(t*16+ln)*PAD + quad*8];
      acc[t] = __builtin_amdgcn_mfma_f32_16x16x32_bf16(a, bb, acc[t], 0,0,0);
    }
    __syncthreads();
  }
  #pragma unroll
  for (int t=0;t<4;t++){
    int j = j0 + t*16 + ln;
    #pragma unroll
    for (int r=0;r<4;r++){
      int i = i0 + w*16 + quad*4 + r;
      e[(size_t)b*SL*SL + (size_t)i*SL + j] = acc[t][r];
    }
  }
}

// ---------- fused maxes + normalized masked softmax weights ----------
// Rm[i] = max_j e[i][j]; Cmx[j] = max_i e[i][j]
// Pa[j][i] = [i<l1] exp(e[i][j]-Rm[j]) / Sa[j],  Sa[j]=sum_{i<l1} exp(e[i][j]-Rm[j])
// Pb[i][j] = [j<l2] exp(e[i][j]-Cmx[i]) / Sb[i], Sb[i]=sum_{j<l2} exp(e[i][j]-Cmx[i])
__global__ __launch_bounds__(256) void softmax_all(
    const float* __restrict__ e, const int* __restrict__ len1, const int* __restrict__ len2,
    short* __restrict__ Pa, short* __restrict__ Pb)
{
  __shared__ float Rm[256], Cmx[256], Sa[256], Sb[256];
  __shared__ float Pt[4][64];
  __shared__ float tile[64][65];
  const int b=blockIdx.x, tid=threadIdx.x, lane=tid&63, w=tid>>6;
  const float* eb = e + (size_t)b*SL*SL;
  const int l1 = len1[b], l2 = len2[b];
  Rm[tid] = -INFINITY; Sb[tid] = 0.f;
  __syncthreads();
  // pass 1: maxes
  for (int tj=0;tj<4;tj++){
    const int c = tj*64+lane;
    float cmax = -INFINITY;
    for (int it=0;it<64;it++){
      const int i = it*4+w;
      float v = eb[(size_t)i*SL + c];
      cmax = fmaxf(cmax, v);
      float m = v;
      m=fmaxf(m,__shfl_xor(m,1));  m=fmaxf(m,__shfl_xor(m,2));
      m=fmaxf(m,__shfl_xor(m,4));  m=fmaxf(m,__shfl_xor(m,8));
      m=fmaxf(m,__shfl_xor(m,16)); m=fmaxf(m,__shfl_xor(m,32));
      if (lane==0) Rm[i] = fmaxf(Rm[i], m);
    }
    Pt[w][lane] = cmax;
    __syncthreads();
    if (w==0) Cmx[c] = fmaxf(fmaxf(Pt[0][lane],Pt[1][lane]), fmaxf(Pt[2][lane],Pt[3][lane]));
    __syncthreads();
  }
  // pass 2: sums
  for (int tj=0;tj<4;tj++){
    const int c = tj*64+lane;
    const float rmc = Rm[c];
    float csum = 0.f;
    for (int it=0;it<64;it++){
      const int i = it*4+w;
      float v = eb[(size_t)i*SL + c];
      if (i < l1) csum += __expf(fminf(v - rmc, 85.f));
      float t_ = (c < l2) ? __expf(fminf(v - Cmx[i], 85.f)) : 0.f;
      t_+=__shfl_xor(t_,1); t_+=__shfl_xor(t_,2); t_+=__shfl_xor(t_,4);
      t_+=__shfl_xor(t_,8); t_+=__shfl_xor(t_,16); t_+=__shfl_xor(t_,32);
      if (lane==0) Sb[i] += t_;
    }
    Pt[w][lane] = csum;
    __syncthreads();
    if (w==0) Sa[c] = Pt[0][lane]+Pt[1][lane]+Pt[2][lane]+Pt[3][lane];
    __syncthreads();
  }
  { float s=Sa[tid]; Sa[tid] = (s>0.f)? 1.f/s : 0.f;
    s=Sb[tid];       Sb[tid] = (s>0.f)? 1.f/s : 0.f; }
  __syncthreads();
  // pass 3: write Pb (row-major) + Pa (transposed via LDS tile)
  for (int ti=0;ti<4;ti++) for (int tj=0;tj<4;tj++){
    #pragma unroll
    for (int it=0;it<16;it++){
      int r=it*4+w, c=lane;
      int i=ti*64+r, j=tj*64+c;
      float v = eb[(size_t)i*SL + j];
      float pb = (j<l2) ? __expf(fminf(v - Cmx[i],85.f))*Sb[i] : 0.f;
      Pb[(size_t)b*SL*SL + (size_t)i*SL + j] = f2b(pb);
      float pa = (i<l1) ? __expf(fminf(v - Rm[j],85.f))*Sa[j] : 0.f;
      tile[r][c] = pa;
    }
    __syncthreads();
    #pragma unroll
    for (int it=0;it<16;it++){
      int rr=it*4+w, cc=lane;
      Pa[(size_t)b*SL*SL + (size_t)(tj*64+rr)*SL + (ti*64+cc)] = f2b(tile[cc][rr]);
    }
    __syncthreads();
  }
}

// ---------- Out[m][0:300] = [m<len] * sum_k P[m][k] * embb[idx[k]][:], both sides ----------
__global__ __launch_bounds__(256) void pe_gemm(
    const short* __restrict__ Pa, const short* __restrict__ Pb,
    const int* __restrict__ s1, const int* __restrict__ s2,
    const int* __restrict__ len2, const int* __restrict__ len1,
    const short* __restrict__ embb, short* __restrict__ al, short* __restrict__ be, int nbc)
{
  constexpr int NT = 19, BNP = 304;
  __shared__ __align__(16) short As[64*PAD];
  __shared__ __align__(16) short Bs[BNP*PAD];
  __shared__ int IdxS[256];
  const int side = (blockIdx.y >= nbc) ? 1 : 0;
  const int b = blockIdx.y - side*nbc;
  const int row0 = blockIdx.x*64;
  const int tid=threadIdx.x, lane=tid&63, w=tid>>6, quad=lane>>4, ln=lane&15;
  const short* P = (side ? Pb : Pa) + (size_t)b*SL*SL;
  const int* idx = side ? s2 : s1;
  const int* lenArr = side ? len1 : len2;
  short* Out = side ? be : al;
  IdxS[tid] = idx[b*SL + tid];
  __syncthreads();
  const int r_ = tid>>2, c_ = tid&3;
  f32x4 acc[NT];
  #pragma unroll
  for (int t=0;t<NT;t++) acc[t]=(f32x4){0.f,0.f,0.f,0.f};
  for (int ks=0; ks<8; ks++){
    const int k0 = ks*32;
    *(short8*)&As[r_*PAD + c_*8] = *(const short8*)&P[(size_t)(row0+r_)*SL + k0 + c_*8];
    for (int it=0; it<38; it++){
      int p = it*256+tid, kk = p/BNP, n = p-kk*BNP;
      Bs[n*PAD+kk] = embb[(size_t)IdxS[k0+kk]*EP + n];
    }
    __syncthreads();
    short8 a = *(const short8*)&As[(w*16+ln)*PAD + quad*8];
    #pragma unroll
    for (int t=0;t<NT;t++){
      short8 bb = *(const short8*)&Bs[(t*16+ln)*PAD + quad*8];
      acc[t] = __builtin_amdgcn_mfma_f32_16x16x32_bf16(a, bb, acc[t], 0,0,0);
    }
    __syncthreads();
  }
  const int lenv = lenArr[b];
  #pragma unroll
  for (int t=0;t<NT;t++){
    int col = t*16+ln;
    #pragma unroll
    for (int r=0;r<4;r++){
      int pos = row0 + w*16 + quad*4 + r;
      float v = (col<ED && pos<lenv) ? acc[t][r] : 0.f;
      Out[((size_t)b*SL + pos)*EP + col] = f2b(v);
    }
  }
  if (tid < 128){ int r=tid>>1, c=tid&1;
    short8 z = {0,0,0,0,0,0,0,0};
    *(short8*)&Out[((size_t)b*SL + row0 + r)*EP + 304 + c*8] = z; }
}

// ---------- aggregate ----------
__global__ __launch_bounds__(256) void aggregate(
    const float* __restrict__ v1, const float* __restrict__ v2,
    const float* __restrict__ W1g, const float* __restrict__ b1g,
    const float* __restrict__ W2g, const float* __restrict__ b2g,
    float* __restrict__ out)
{
  __shared__ float z[2*HD];
  __shared__ float a[HD];
  const int b = blockIdx.x, t = threadIdx.x;
  if (t < HD){ z[t] = v1[b*HD+t]; z[HD+t] = v2[b*HD+t]; }
  __syncthreads();
  if (t < HD){
    float acc = b1g[t];
    for (int k=0;k<2*HD;k++) acc += z[k]*W1g[(size_t)k*HD+t];
    a[t] = fmaxf(acc, 0.f);
  }
  __syncthreads();
  if (t < 2){
    float acc = b2g[t];
    for (int k=0;k<HD;k++) acc += a[k]*W2g[k*2+t];
    out[b*2+t] = acc;
  }
}

extern "C" void kernel_launch(void* const* d_in, const int* in_sizes, int n_in,
                              void* d_out, int out_size, void* d_ws, size_t ws_size,
                              hipStream_t stream) {
  const float* emb = (const float*)d_in[0];
  const float* W1a = (const float*)d_in[1];  const float* b1a = (const float*)d_in[2];
  const float* W2a = (const float*)d_in[3];  const float* b2a = (const float*)d_in[4];
  const float* W1c = (const float*)d_in[5];  const float* b1c = (const float*)d_in[6];
  const float* W2c = (const float*)d_in[7];  const float* b2c = (const float*)d_in[8];
  const float* W1g = (const float*)d_in[9];  const float* b1g = (const float*)d_in[10];
  const float* W2g = (const float*)d_in[11]; const float* b2g = (const float*)d_in[12];
  const int* s1 = (const int*)d_in[13];
  const int* s2 = (const int*)d_in[14];
  const int* len1 = (const int*)d_in[15];
  const int* len2 = (const int*)d_in[16];
  float* out = (float*)d_out;
  char* W = (char*)d_ws;

  // ---- fixed region ----
  float* v1   = (float*)(W);                      // 409,600
  float* v2   = (float*)(W + 409600);             // 409,600
  short* embb = (short*)(W + 819200);             // 50000*320*2 = 32,000,000
  short* W1at = (short*)(W + 32819200);           // 208*320*2 = 133,120
  short* W2at = (short*)(W + 32952320);           // 208*224*2 =  93,184
  short* W1ct = (short*)(W + 33045504);           // 208*640*2 = 266,240
  short* W2ct = (short*)(W + 33311744);           // 208*224*2 =  93,184
  char*  C0   = W + 33404928;
  const size_t FIXED = 33404928ull;

  // ---- per-batch chunked region ----
  // h1/h2: 256*224*2 = 114,688 ea; e: 262,144; Pa/Pb: 131,072 ea; al/be: 256*320*2 = 163,840 ea
  const size_t PERB = 1081344ull;
  int nbc = NB;
  while (nbc > 1 && FIXED + (size_t)nbc*PERB > ws_size) nbc >>= 1;
  const size_t nb = (size_t)nbc;
  short* h1 = (short*)(C0);
  short* h2 = (short*)(C0 + nb*114688);
  float* e  = (float*)(C0 + nb*229376);
  short* Pa = (short*)(C0 + nb*491520);
  short* Pb = (short*)(C0 + nb*622592);
  short* al = (short*)(C0 + nb*753664);
  short* be = (short*)(C0 + nb*917504);

  const dim3 blk(256);
  hipMemsetAsync(v1, 0, 2ull*NB*HD*sizeof(float), stream);
  // one-time conversions
  conv_emb<<<dim3((50000*EP+255)/256), blk, 0, stream>>>(emb, embb);
  convT_plain<<<dim3((208*EP+255)/256), blk, 0, stream>>>(W1a, W1at, ED, EP);
  convT_plain<<<dim3((208*HP+255)/256), blk, 0, stream>>>(W2a, W2at, HD, HP);
  convT_split<<<dim3((208*640+255)/256), blk, 0, stream>>>(W1c, W1ct);
  convT_plain<<<dim3((208*HP+255)/256), blk, 0, stream>>>(W2c, W2ct, HD, HP);

  const int chunks = NB / nbc;
  for (int c = 0; c < chunks; c++){
    const int b0 = c * nbc;
    const int* s1c = s1 + (size_t)b0*SL;
    const int* s2c = s2 + (size_t)b0*SL;
    const int* l1c = len1 + b0;
    const int* l2c = len2 + b0;

    // attend (both sides, both layers fused): h1 <- s1, h2 <- s2
    mlp2<EP,1,false><<<dim3(8*nbc), blk, 0, stream>>>(
        embb, s1c, s2c, nullptr, nullptr, W1at, b1a, W2at, b2a,
        h1, h2, nullptr, nullptr, nullptr, nullptr);
    // scores + softmax weights
    scores_gemm<<<dim3(4,4,nbc), blk, 0, stream>>>(h1, h2, e);
    softmax_all<<<dim3(nbc), blk, 0, stream>>>(e, l1c, l2c, Pa, Pb);
    // alphas (Pa @ e1, mask len2) and betas (Pb @ e2, mask len1), one launch
    pe_gemm<<<dim3(4, 2*nbc), blk, 0, stream>>>(Pa, Pb, s1c, s2c, l2c, l1c, embb, al, be, nbc);
    // compare (both sides, both layers fused, masked row-sum epilogue)
    mlp2<640,2,true><<<dim3(8*nbc), blk, 0, stream>>>(
        embb, s1c, s2c, be, al, W1ct, b1c, W2ct, b2c,
        nullptr, nullptr, l1c, l2c, v1 + (size_t)b0*HD, v2 + (size_t)b0*HD);
  }
  aggregate<<<dim3(NB), blk, 0, stream>>>(v1, v2, W1g, b1g, W2g, b2g, out);
}

// Round 6
// 1683.462 us; speedup vs baseline: 3.6442x; 1.6100x over previous
//
#include <hip/hip_runtime.h>
#include <hip/hip_bf16.h>

#define DEV static __device__ __forceinline__

typedef short short8 __attribute__((ext_vector_type(8)));
typedef short short4v __attribute__((ext_vector_type(4)));
typedef float f32x4 __attribute__((ext_vector_type(4)));

#define NB 512
#define SL 256
#define ED 300
#define HD 200
#define EP 320   // padded embed / concat-half / alpha-beta stride
#define HP 224   // padded hidden stride (200 -> 224)
#define TSP 232  // LDS layer-1 output tile stride
#define PAD 40

DEV short f2b(float f){ __hip_bfloat16 h = __float2bfloat16(f); short s; __builtin_memcpy(&s,&h,2); return s; }

// ---------- one-time conversions ----------
__global__ __launch_bounds__(256) void conv_emb(const float* __restrict__ src, short* __restrict__ dst){
  size_t g = (size_t)blockIdx.x*256 + threadIdx.x;
  if (g >= (size_t)50000*EP) return;
  int row = (int)(g/EP), k = (int)(g%EP);
  dst[g] = (k<ED) ? f2b(src[(size_t)row*ED + k]) : (short)0;
}
__global__ __launch_bounds__(256) void convT_plain(const float* __restrict__ W, short* __restrict__ Wt,
                                                   int Kreal, int KP){
  int g = blockIdx.x*256 + threadIdx.x;
  if (g >= 208*KP) return;
  int n = g/KP, k = g%KP;
  float v = (n<HD && k<Kreal) ? W[(size_t)k*HD + n] : 0.f;
  Wt[g] = f2b(v);
}
__global__ __launch_bounds__(256) void convT_split(const float* __restrict__ W, short* __restrict__ Wt){
  int g = blockIdx.x*256 + threadIdx.x;
  if (g >= 208*640) return;
  int n = g/640, k = g%640;
  int half = (k>=EP);
  int kk = k - half*EP;
  float v = (n<HD && kk<ED) ? W[(size_t)(half*ED+kk)*HD + n] : 0.f;
  Wt[g] = f2b(v);
}

// ---------- fused 2-layer MLP, both sides in one launch ----------
template<int KP1, int AMODE, bool DO_SUM>
__global__ __launch_bounds__(256) void mlp2(
    const short* __restrict__ embb,
    const int* __restrict__ idxA, const int* __restrict__ idxB,
    const short* __restrict__ XtraA, const short* __restrict__ XtraB,
    const short* __restrict__ W1t, const float* __restrict__ b1,
    const short* __restrict__ W2t, const float* __restrict__ b2,
    short* __restrict__ OutA, short* __restrict__ OutB,
    const int* __restrict__ lenA, const int* __restrict__ lenB,
    float* __restrict__ VA, float* __restrict__ VB)
{
  __shared__ __align__(16) short As[64*PAD];
  __shared__ __align__(16) short Bs[208*PAD];
  __shared__ __align__(16) short Ts[64*TSP];
  __shared__ int IdxS[64];
  const int tid=threadIdx.x, lane=tid&63, w=tid>>6, quad=lane>>4, ln=lane&15;
  const int half = gridDim.x>>1;
  const int side = (blockIdx.x >= half) ? 1 : 0;
  const int row0 = (blockIdx.x - side*half)*64;
  const int* idx = side ? idxB : idxA;
  const short* Xtra = side ? XtraB : XtraA;
  if (tid < 64) IdxS[tid] = idx[row0+tid];
  if (tid < 128){ int r=tid>>1, c=tid&1;
    short8 z = {0,0,0,0,0,0,0,0};
    *(short8*)&Ts[r*TSP + 208 + c*8] = z; }
  __syncthreads();

  f32x4 acc[13];
  #pragma unroll
  for (int t=0;t<13;t++) acc[t]=(f32x4){0.f,0.f,0.f,0.f};
  const int r_ = tid>>2, c_ = tid&3;

  // ---- layer 1 ----
  for (int ks=0; ks<KP1/32; ks++){
    const int k0 = ks*32;
    short8 av;
    if constexpr (AMODE==1){
      av = *(const short8*)&embb[(size_t)IdxS[r_]*EP + k0 + c_*8];
    } else {
      if (k0 < EP) av = *(const short8*)&embb[(size_t)IdxS[r_]*EP + k0 + c_*8];
      else         av = *(const short8*)&Xtra[(size_t)(row0+r_)*EP + (k0-EP) + c_*8];
    }
    *(short8*)&As[r_*PAD + c_*8] = av;
    #pragma unroll
    for (int it=0; it<4; it++){
      int p = it*256+tid, n = p>>2, cc = p&3;
      if (n < 208)
        *(short8*)&Bs[n*PAD + cc*8] = *(const short8*)&W1t[(size_t)n*KP1 + k0 + cc*8];
    }
    __syncthreads();
    short8 a = *(const short8*)&As[(w*16+ln)*PAD + quad*8];
    #pragma unroll
    for (int t=0;t<13;t++){
      short8 bb = *(const short8*)&Bs[(t*16+ln)*PAD + quad*8];
      acc[t] = __builtin_amdgcn_mfma_f32_16x16x32_bf16(a, bb, acc[t], 0,0,0);
    }
    __syncthreads();
  }
  #pragma unroll
  for (int t=0;t<13;t++){
    int col = t*16+ln;
    float bv = (col<HD) ? b1[col] : 0.f;
    #pragma unroll
    for (int r=0;r<4;r++){
      int rl = w*16+quad*4+r;
      float v = (col<HD) ? fmaxf(acc[t][r]+bv, 0.f) : 0.f;
      Ts[rl*TSP + col] = f2b(v);
    }
    acc[t]=(f32x4){0.f,0.f,0.f,0.f};
  }
  // ---- layer 2 (K=224) ----
  for (int ks=0; ks<7; ks++){
    const int k0 = ks*32;
    #pragma unroll
    for (int it=0; it<4; it++){
      int p = it*256+tid, n = p>>2, cc = p&3;
      if (n < 208)
        *(short8*)&Bs[n*PAD + cc*8] = *(const short8*)&W2t[(size_t)n*HP + k0 + cc*8];
    }
    __syncthreads();
    short8 a = *(const short8*)&Ts[(w*16+ln)*TSP + k0 + quad*8];
    #pragma unroll
    for (int t=0;t<13;t++){
      short8 bb = *(const short8*)&Bs[(t*16+ln)*PAD + quad*8];
      acc[t] = __builtin_amdgcn_mfma_f32_16x16x32_bf16(a, bb, acc[t], 0,0,0);
    }
    __syncthreads();
  }
  if constexpr (!DO_SUM){
    short* Out = side ? OutB : OutA;
    #pragma unroll
    for (int t=0;t<13;t++){
      int col = t*16+ln;
      float bv = (col<HD) ? b2[col] : 0.f;
      #pragma unroll
      for (int r=0;r<4;r++){
        int rl = w*16+quad*4+r;
        float v = (col<HD) ? fmaxf(acc[t][r]+bv, 0.f) : 0.f;
        Out[(size_t)(row0+rl)*HP + col] = f2b(v);
      }
    }
    if (tid < 128){ int r=tid>>1, c=tid&1;
      short8 z = {0,0,0,0,0,0,0,0};
      *(short8*)&Out[(size_t)(row0+r)*HP + 208 + c*8] = z; }
  } else {
    const int* lenArr = side ? lenB : lenA;
    float* V = side ? VB : VA;
    const int b = row0>>8;
    const int lenv = lenArr[b];
    const int posBase = (row0&255) + w*16 + quad*4;
    #pragma unroll
    for (int t=0;t<13;t++){
      int col = t*16+ln;
      float bv = (col<HD) ? b2[col] : 0.f;
      float s = 0.f;
      #pragma unroll
      for (int r=0;r<4;r++){
        float v = fmaxf(acc[t][r]+bv, 0.f);
        if (posBase + r < lenv) s += v;
      }
      s += __shfl_xor(s,16);
      s += __shfl_xor(s,32);
      if (quad==0 && col<HD) atomicAdd(&V[b*HD+col], s);
    }
  }
}

// ---------- scores: e[b][i][j] = sum_k h1[b][i][k]*h2[b][j][k] ----------
__global__ __launch_bounds__(256) void scores_gemm(
    const short* __restrict__ h1, const short* __restrict__ h2, float* __restrict__ e)
{
  __shared__ __align__(16) short As[64*PAD];
  __shared__ __align__(16) short Bs[64*PAD];
  const int b = blockIdx.z;
  const int i0 = blockIdx.x*64, j0 = blockIdx.y*64;
  const int tid=threadIdx.x, lane=tid&63, w=tid>>6, quad=lane>>4, ln=lane&15;
  const int r_ = tid>>2, c_ = tid&3;
  f32x4 acc[4];
  #pragma unroll
  for (int t=0;t<4;t++) acc[t]=(f32x4){0.f,0.f,0.f,0.f};
  for (int ks=0; ks<7; ks++){
    const int k0 = ks*32;
    *(short8*)&As[r_*PAD + c_*8] = *(const short8*)&h1[((size_t)b*SL + i0 + r_)*HP + k0 + c_*8];
    *(short8*)&Bs[r_*PAD + c_*8] = *(const short8*)&h2[((size_t)b*SL + j0 + r_)*HP + k0 + c_*8];
    __syncthreads();
    short8 a = *(const short8*)&As[(w*16+ln)*PAD + quad*8];
    #pragma unroll
    for (int t=0;t<4;t++){
      short8 bb = *(const short8*)&Bs[(t*16+ln)*PAD + quad*8];
      acc[t] = __builtin_amdgcn_mfma_f32_16x16x32_bf16(a, bb, acc[t], 0,0,0);
    }
    __syncthreads();
  }
  #pragma unroll
  for (int t=0;t<4;t++){
    int j = j0 + t*16 + ln;
    #pragma unroll
    for (int r=0;r<4;r++){
      int i = i0 + w*16 + quad*4 + r;
      e[(size_t)b*SL*SL + (size_t)i*SL + j] = acc[t][r];
    }
  }
}

// ---------- maxes: RowMax[i]=max_j e[i][j]; ColMax[j]=max_i e[i][j] ----------
// grid (4, 2, nbc)
__global__ __launch_bounds__(256) void maxes_k(
    const float* __restrict__ e, float* __restrict__ RowMax, float* __restrict__ ColMax)
{
  const int b = blockIdx.z, s = blockIdx.x, ori = blockIdx.y;
  const float* eb = e + (size_t)b*SL*SL;
  const int tid = threadIdx.x, lane = tid&63, w = tid>>6;
  if (ori == 0){
    #pragma unroll 4
    for (int t=0;t<16;t++){
      int i = s*64 + w*16 + t;
      float4 v = ((const float4*)(eb + (size_t)i*SL))[lane];
      float m = fmaxf(fmaxf(v.x,v.y), fmaxf(v.z,v.w));
      m=fmaxf(m,__shfl_xor(m,1));  m=fmaxf(m,__shfl_xor(m,2));
      m=fmaxf(m,__shfl_xor(m,4));  m=fmaxf(m,__shfl_xor(m,8));
      m=fmaxf(m,__shfl_xor(m,16)); m=fmaxf(m,__shfl_xor(m,32));
      if (lane==0) RowMax[b*SL+i] = m;
    }
  } else {
    __shared__ float Part[4][64];
    const int j = s*64 + lane;
    float m = -INFINITY;
    for (int i=w; i<SL; i+=4) m = fmaxf(m, eb[(size_t)i*SL + j]);
    Part[w][lane] = m;
    __syncthreads();
    if (w==0)
      ColMax[b*SL+j] = fmaxf(fmaxf(Part[0][lane],Part[1][lane]),
                             fmaxf(Part[2][lane],Part[3][lane]));
  }
}

// ---------- P weights, normalized + masked ----------
// side0: Pb[i][j] = [j<l2] exp(e[i][j]-ColMax[i]) / sum_j(...)
// side1: Pa[j][i] = [i<l1] exp(e[i][j]-RowMax[j]) / sum_i(...)   (Pa row-major in j, contiguous i)
// grid (4, 2, nbc)
__global__ __launch_bounds__(256) void pwrite_k(
    const float* __restrict__ e, const float* __restrict__ RowMax, const float* __restrict__ ColMax,
    const int* __restrict__ len1, const int* __restrict__ len2,
    short* __restrict__ Pa, short* __restrict__ Pb)
{
  const int b = blockIdx.z, s = blockIdx.x, ori = blockIdx.y;
  const float* eb = e + (size_t)b*SL*SL;
  const int tid = threadIdx.x, lane = tid&63, w = tid>>6;
  if (ori == 0){
    const int l2 = len2[b];
    for (int t=0;t<16;t++){
      int i = s*64 + w*16 + t;
      float cm = ColMax[b*SL+i];
      float4 v = ((const float4*)(eb + (size_t)i*SL))[lane];
      int c0 = lane*4;
      float e0 = (c0+0<l2) ? __expf(fminf(v.x-cm,85.f)) : 0.f;
      float e1 = (c0+1<l2) ? __expf(fminf(v.y-cm,85.f)) : 0.f;
      float e2 = (c0+2<l2) ? __expf(fminf(v.z-cm,85.f)) : 0.f;
      float e3 = (c0+3<l2) ? __expf(fminf(v.w-cm,85.f)) : 0.f;
      float ss = e0+e1+e2+e3;
      ss+=__shfl_xor(ss,1); ss+=__shfl_xor(ss,2); ss+=__shfl_xor(ss,4);
      ss+=__shfl_xor(ss,8); ss+=__shfl_xor(ss,16); ss+=__shfl_xor(ss,32);
      float inv = (ss>0.f) ? 1.f/ss : 0.f;
      short4v o; o[0]=f2b(e0*inv); o[1]=f2b(e1*inv); o[2]=f2b(e2*inv); o[3]=f2b(e3*inv);
      ((short4v*)(Pb + (size_t)b*SL*SL + (size_t)i*SL))[lane] = o;
    }
  } else {
    __shared__ float Part[4][64];
    __shared__ float SaInv[64];
    __shared__ float RmS[64];
    __shared__ float Tile[64][65];
    const int l1 = len1[b];
    const int j0 = s*64;
    if (tid < 64) RmS[tid] = RowMax[b*SL + j0 + tid];
    __syncthreads();
    {
      float sum = 0.f;
      for (int i=w; i<SL; i+=4)
        if (i < l1) sum += __expf(fminf(eb[(size_t)i*SL + j0 + lane] - RmS[lane], 85.f));
      Part[w][lane] = sum;
    }
    __syncthreads();
    if (w==0){
      float s_ = Part[0][lane]+Part[1][lane]+Part[2][lane]+Part[3][lane];
      SaInv[lane] = (s_>0.f) ? 1.f/s_ : 0.f;
    }
    __syncthreads();
    for (int ti=0; ti<4; ti++){
      const int i0 = ti*64;
      #pragma unroll 4
      for (int it=0; it<16; it++){
        int il = it*4 + w;
        int i = i0 + il;
        float v = eb[(size_t)i*SL + j0 + lane];
        float p = (i<l1) ? __expf(fminf(v - RmS[lane],85.f))*SaInv[lane] : 0.f;
        Tile[il][lane] = p;
      }
      __syncthreads();
      {
        int jl = tid>>2, q = tid&3;
        short8 o1, o2;
        #pragma unroll
        for (int u=0;u<8;u++){
          o1[u] = f2b(Tile[q*16+u][jl]);
          o2[u] = f2b(Tile[q*16+8+u][jl]);
        }
        short* dst = Pa + (size_t)b*SL*SL + (size_t)(j0+jl)*SL + i0 + q*16;
        *(short8*)dst = o1;
        *(short8*)(dst+8) = o2;
      }
      __syncthreads();
    }
  }
}

// ---------- Out[m][0:300] = [m<len] * sum_k P[m][k] * embb[idx[k]][:], both sides ----------
__global__ __launch_bounds__(256) void pe_gemm(
    const short* __restrict__ Pa, const short* __restrict__ Pb,
    const int* __restrict__ s1, const int* __restrict__ s2,
    const int* __restrict__ len2, const int* __restrict__ len1,
    const short* __restrict__ embb, short* __restrict__ al, short* __restrict__ be, int nbc)
{
  constexpr int NT = 19, BNP = 304;
  __shared__ __align__(16) short As[64*PAD];
  __shared__ __align__(16) short Bs[BNP*PAD];
  __shared__ int IdxS[256];
  const int side = (blockIdx.y >= nbc) ? 1 : 0;
  const int b = blockIdx.y - side*nbc;
  const int row0 = blockIdx.x*64;
  const int tid=threadIdx.x, lane=tid&63, w=tid>>6, quad=lane>>4, ln=lane&15;
  const short* P = (side ? Pb : Pa) + (size_t)b*SL*SL;
  const int* idx = side ? s2 : s1;
  const int* lenArr = side ? len1 : len2;
  short* Out = side ? be : al;
  IdxS[tid] = idx[b*SL + tid];
  __syncthreads();
  const int r_ = tid>>2, c_ = tid&3;
  f32x4 acc[NT];
  #pragma unroll
  for (int t=0;t<NT;t++) acc[t]=(f32x4){0.f,0.f,0.f,0.f};
  for (int ks=0; ks<8; ks++){
    const int k0 = ks*32;
    *(short8*)&As[r_*PAD + c_*8] = *(const short8*)&P[(size_t)(row0+r_)*SL + k0 + c_*8];
    for (int it=0; it<38; it++){
      int p = it*256+tid, kk = p/BNP, n = p-kk*BNP;
      Bs[n*PAD+kk] = embb[(size_t)IdxS[k0+kk]*EP + n];
    }
    __syncthreads();
    short8 a = *(const short8*)&As[(w*16+ln)*PAD + quad*8];
    #pragma unroll
    for (int t=0;t<NT;t++){
      short8 bb = *(const short8*)&Bs[(t*16+ln)*PAD + quad*8];
      acc[t] = __builtin_amdgcn_mfma_f32_16x16x32_bf16(a, bb, acc[t], 0,0,0);
    }
    __syncthreads();
  }
  const int lenv = lenArr[b];
  #pragma unroll
  for (int t=0;t<NT;t++){
    int col = t*16+ln;
    #pragma unroll
    for (int r=0;r<4;r++){
      int pos = row0 + w*16 + quad*4 + r;
      float v = (col<ED && pos<lenv) ? acc[t][r] : 0.f;
      Out[((size_t)b*SL + pos)*EP + col] = f2b(v);
    }
  }
  if (tid < 128){ int r=tid>>1, c=tid&1;
    short8 z = {0,0,0,0,0,0,0,0};
    *(short8*)&Out[((size_t)b*SL + row0 + r)*EP + 304 + c*8] = z; }
}

// ---------- aggregate ----------
__global__ __launch_bounds__(256) void aggregate(
    const float* __restrict__ v1, const float* __restrict__ v2,
    const float* __restrict__ W1g, const float* __restrict__ b1g,
    const float* __restrict__ W2g, const float* __restrict__ b2g,
    float* __restrict__ out)
{
  __shared__ float z[2*HD];
  __shared__ float a[HD];
  const int b = blockIdx.x, t = threadIdx.x;
  if (t < HD){ z[t] = v1[b*HD+t]; z[HD+t] = v2[b*HD+t]; }
  __syncthreads();
  if (t < HD){
    float acc = b1g[t];
    for (int k=0;k<2*HD;k++) acc += z[k]*W1g[(size_t)k*HD+t];
    a[t] = fmaxf(acc, 0.f);
  }
  __syncthreads();
  if (t < 2){
    float acc = b2g[t];
    for (int k=0;k<HD;k++) acc += a[k]*W2g[k*2+t];
    out[b*2+t] = acc;
  }
}

extern "C" void kernel_launch(void* const* d_in, const int* in_sizes, int n_in,
                              void* d_out, int out_size, void* d_ws, size_t ws_size,
                              hipStream_t stream) {
  const float* emb = (const float*)d_in[0];
  const float* W1a = (const float*)d_in[1];  const float* b1a = (const float*)d_in[2];
  const float* W2a = (const float*)d_in[3];  const float* b2a = (const float*)d_in[4];
  const float* W1c = (const float*)d_in[5];  const float* b1c = (const float*)d_in[6];
  const float* W2c = (const float*)d_in[7];  const float* b2c = (const float*)d_in[8];
  const float* W1g = (const float*)d_in[9];  const float* b1g = (const float*)d_in[10];
  const float* W2g = (const float*)d_in[11]; const float* b2g = (const float*)d_in[12];
  const int* s1 = (const int*)d_in[13];
  const int* s2 = (const int*)d_in[14];
  const int* len1 = (const int*)d_in[15];
  const int* len2 = (const int*)d_in[16];
  float* out = (float*)d_out;
  char* W = (char*)d_ws;

  // ---- fixed region ----
  float* v1   = (float*)(W);                      // 409,600
  float* v2   = (float*)(W + 409600);             // 409,600
  short* embb = (short*)(W + 819200);             // 32,000,000
  short* W1at = (short*)(W + 32819200);           // 133,120
  short* W2at = (short*)(W + 32952320);           //  93,184
  short* W1ct = (short*)(W + 33045504);           // 266,240
  short* W2ct = (short*)(W + 33311744);           //  93,184
  char*  C0   = W + 33404928;
  const size_t FIXED = 33404928ull;

  // ---- per-batch chunked region ----
  // h1/h2 114688 ea; e 262144; Pa/Pb 131072 ea; al/be 163840 ea; Rm/Cm 1024 ea
  const size_t PERB = 1083392ull;
  int nbc = NB;
  while (nbc > 1 && FIXED + (size_t)nbc*PERB > ws_size) nbc >>= 1;
  const size_t nb = (size_t)nbc;
  short* h1 = (short*)(C0);
  short* h2 = (short*)(C0 + nb*114688);
  float* e  = (float*)(C0 + nb*229376);
  short* Pa = (short*)(C0 + nb*491520);
  short* Pb = (short*)(C0 + nb*622592);
  short* al = (short*)(C0 + nb*753664);
  short* be = (short*)(C0 + nb*917504);
  float* Rm = (float*)(C0 + nb*1081344);
  float* Cm = (float*)(C0 + nb*1082368);

  const dim3 blk(256);
  hipMemsetAsync(v1, 0, 2ull*NB*HD*sizeof(float), stream);
  conv_emb<<<dim3((50000*EP+255)/256), blk, 0, stream>>>(emb, embb);
  convT_plain<<<dim3((208*EP+255)/256), blk, 0, stream>>>(W1a, W1at, ED, EP);
  convT_plain<<<dim3((208*HP+255)/256), blk, 0, stream>>>(W2a, W2at, HD, HP);
  convT_split<<<dim3((208*640+255)/256), blk, 0, stream>>>(W1c, W1ct);
  convT_plain<<<dim3((208*HP+255)/256), blk, 0, stream>>>(W2c, W2ct, HD, HP);

  const int chunks = NB / nbc;
  for (int c = 0; c < chunks; c++){
    const int b0 = c * nbc;
    const int* s1c = s1 + (size_t)b0*SL;
    const int* s2c = s2 + (size_t)b0*SL;
    const int* l1c = len1 + b0;
    const int* l2c = len2 + b0;

    mlp2<EP,1,false><<<dim3(8*nbc), blk, 0, stream>>>(
        embb, s1c, s2c, nullptr, nullptr, W1at, b1a, W2at, b2a,
        h1, h2, nullptr, nullptr, nullptr, nullptr);
    scores_gemm<<<dim3(4,4,nbc), blk, 0, stream>>>(h1, h2, e);
    maxes_k<<<dim3(4,2,nbc), blk, 0, stream>>>(e, Rm, Cm);
    pwrite_k<<<dim3(4,2,nbc), blk, 0, stream>>>(e, Rm, Cm, l1c, l2c, Pa, Pb);
    pe_gemm<<<dim3(4, 2*nbc), blk, 0, stream>>>(Pa, Pb, s1c, s2c, l2c, l1c, embb, al, be, nbc);
    mlp2<640,2,true><<<dim3(8*nbc), blk, 0, stream>>>(
        embb, s1c, s2c, be, al, W1ct, b1c, W2ct, b2c,
        nullptr, nullptr, l1c, l2c, v1 + (size_t)b0*HD, v2 + (size_t)b0*HD);
  }
  aggregate<<<dim3(NB), blk, 0, stream>>>(v1, v2, W1g, b1g, W2g, b2g, out);
}

// Round 7
// 1301.125 us; speedup vs baseline: 4.7150x; 1.2939x over previous
//
#include <hip/hip_runtime.h>
#include <hip/hip_bf16.h>

#define DEV static __device__ __forceinline__

typedef short short8 __attribute__((ext_vector_type(8)));
typedef short short4v __attribute__((ext_vector_type(4)));
typedef float f32x4 __attribute__((ext_vector_type(4)));

#define NB 512
#define SL 256
#define ED 300
#define HD 200
#define EP 320   // padded embed stride
#define HP 224   // padded hidden stride
#define TSP 232  // LDS layer-1 output tile stride
#define PAD 40
#define GSTR 53248   // per-(b,side) Gt size in shorts: 208*256

DEV short f2b(float f){ __hip_bfloat16 h = __float2bfloat16(f); short s; __builtin_memcpy(&s,&h,2); return s; }

// ---------- one-time conversions ----------
__global__ __launch_bounds__(256) void conv_emb(const float* __restrict__ src, short* __restrict__ dst){
  size_t g = (size_t)blockIdx.x*256 + threadIdx.x;
  if (g >= (size_t)50000*EP) return;
  int row = (int)(g/EP), k = (int)(g%EP);
  dst[g] = (k<ED) ? f2b(src[(size_t)row*ED + k]) : (short)0;
}
// Wt[n][k] (208 x KP) <- W[k][n] (Kreal x 200), zero padded
__global__ __launch_bounds__(256) void convT_plain(const float* __restrict__ W, short* __restrict__ Wt,
                                                   int Kreal, int KP){
  int g = blockIdx.x*256 + threadIdx.x;
  if (g >= 208*KP) return;
  int n = g/KP, k = g%KP;
  float v = (n<HD && k<Kreal) ? W[(size_t)k*HD + n] : 0.f;
  Wt[g] = f2b(v);
}

// ---------- fused 2-layer attend MLP, both sides in one launch ----------
__global__ __launch_bounds__(256) void mlp2(
    const short* __restrict__ embb,
    const int* __restrict__ idxA, const int* __restrict__ idxB,
    const short* __restrict__ W1t, const float* __restrict__ b1,
    const short* __restrict__ W2t, const float* __restrict__ b2,
    short* __restrict__ OutA, short* __restrict__ OutB)
{
  __shared__ __align__(16) short As[64*PAD];
  __shared__ __align__(16) short Bs[208*PAD];
  __shared__ __align__(16) short Ts[64*TSP];
  __shared__ int IdxS[64];
  const int tid=threadIdx.x, lane=tid&63, w=tid>>6, quad=lane>>4, ln=lane&15;
  const int half = gridDim.x>>1;
  const int side = (blockIdx.x >= half) ? 1 : 0;
  const int row0 = (blockIdx.x - side*half)*64;
  const int* idx = side ? idxB : idxA;
  if (tid < 64) IdxS[tid] = idx[row0+tid];
  if (tid < 128){ int r=tid>>1, c=tid&1;
    short8 z = {0,0,0,0,0,0,0,0};
    *(short8*)&Ts[r*TSP + 208 + c*8] = z; }
  __syncthreads();

  f32x4 acc[13];
  #pragma unroll
  for (int t=0;t<13;t++) acc[t]=(f32x4){0.f,0.f,0.f,0.f};
  const int r_ = tid>>2, c_ = tid&3;

  // ---- layer 1 (K=320) ----
  for (int ks=0; ks<10; ks++){
    const int k0 = ks*32;
    *(short8*)&As[r_*PAD + c_*8] = *(const short8*)&embb[(size_t)IdxS[r_]*EP + k0 + c_*8];
    #pragma unroll
    for (int it=0; it<4; it++){
      int p = it*256+tid, n = p>>2, cc = p&3;
      if (n < 208)
        *(short8*)&Bs[n*PAD + cc*8] = *(const short8*)&W1t[(size_t)n*EP + k0 + cc*8];
    }
    __syncthreads();
    short8 a = *(const short8*)&As[(w*16+ln)*PAD + quad*8];
    #pragma unroll
    for (int t=0;t<13;t++){
      short8 bb = *(const short8*)&Bs[(t*16+ln)*PAD + quad*8];
      acc[t] = __builtin_amdgcn_mfma_f32_16x16x32_bf16(a, bb, acc[t], 0,0,0);
    }
    __syncthreads();
  }
  #pragma unroll
  for (int t=0;t<13;t++){
    int col = t*16+ln;
    float bv = (col<HD) ? b1[col] : 0.f;
    #pragma unroll
    for (int r=0;r<4;r++){
      int rl = w*16+quad*4+r;
      float v = (col<HD) ? fmaxf(acc[t][r]+bv, 0.f) : 0.f;
      Ts[rl*TSP + col] = f2b(v);
    }
    acc[t]=(f32x4){0.f,0.f,0.f,0.f};
  }
  // ---- layer 2 (K=224) ----
  for (int ks=0; ks<7; ks++){
    const int k0 = ks*32;
    #pragma unroll
    for (int it=0; it<4; it++){
      int p = it*256+tid, n = p>>2, cc = p&3;
      if (n < 208)
        *(short8*)&Bs[n*PAD + cc*8] = *(const short8*)&W2t[(size_t)n*HP + k0 + cc*8];
    }
    __syncthreads();
    short8 a = *(const short8*)&Ts[(w*16+ln)*TSP + k0 + quad*8];
    #pragma unroll
    for (int t=0;t<13;t++){
      short8 bb = *(const short8*)&Bs[(t*16+ln)*PAD + quad*8];
      acc[t] = __builtin_amdgcn_mfma_f32_16x16x32_bf16(a, bb, acc[t], 0,0,0);
    }
    __syncthreads();
  }
  short* Out = side ? OutB : OutA;
  #pragma unroll
  for (int t=0;t<13;t++){
    int col = t*16+ln;
    float bv = (col<HD) ? b2[col] : 0.f;
    #pragma unroll
    for (int r=0;r<4;r++){
      int rl = w*16+quad*4+r;
      float v = (col<HD) ? fmaxf(acc[t][r]+bv, 0.f) : 0.f;
      Out[(size_t)(row0+rl)*HP + col] = f2b(v);
    }
  }
  if (tid < 128){ int r=tid>>1, c=tid&1;
    short8 z = {0,0,0,0,0,0,0,0};
    *(short8*)&Out[(size_t)(row0+r)*HP + 208 + c*8] = z; }
}

// ---------- scores: e[b][i][j] = sum_k h1[b][i][k]*h2[b][j][k] ----------
__global__ __launch_bounds__(256) void scores_gemm(
    const short* __restrict__ h1, const short* __restrict__ h2, float* __restrict__ e)
{
  __shared__ __align__(16) short As[64*PAD];
  __shared__ __align__(16) short Bs[64*PAD];
  const int b = blockIdx.z;
  const int i0 = blockIdx.x*64, j0 = blockIdx.y*64;
  const int tid=threadIdx.x, lane=tid&63, w=tid>>6, quad=lane>>4, ln=lane&15;
  const int r_ = tid>>2, c_ = tid&3;
  f32x4 acc[4];
  #pragma unroll
  for (int t=0;t<4;t++) acc[t]=(f32x4){0.f,0.f,0.f,0.f};
  for (int ks=0; ks<7; ks++){
    const int k0 = ks*32;
    *(short8*)&As[r_*PAD + c_*8] = *(const short8*)&h1[((size_t)b*SL + i0 + r_)*HP + k0 + c_*8];
    *(short8*)&Bs[r_*PAD + c_*8] = *(const short8*)&h2[((size_t)b*SL + j0 + r_)*HP + k0 + c_*8];
    __syncthreads();
    short8 a = *(const short8*)&As[(w*16+ln)*PAD + quad*8];
    #pragma unroll
    for (int t=0;t<4;t++){
      short8 bb = *(const short8*)&Bs[(t*16+ln)*PAD + quad*8];
      acc[t] = __builtin_amdgcn_mfma_f32_16x16x32_bf16(a, bb, acc[t], 0,0,0);
    }
    __syncthreads();
  }
  #pragma unroll
  for (int t=0;t<4;t++){
    int j = j0 + t*16 + ln;
    #pragma unroll
    for (int r=0;r<4;r++){
      int i = i0 + w*16 + quad*4 + r;
      e[(size_t)b*SL*SL + (size_t)i*SL + j] = acc[t][r];
    }
  }
}

// ---------- maxes: RowMax[i]=max_j e[i][j]; ColMax[j]=max_i e[i][j] ----------
__global__ __launch_bounds__(256) void maxes_k(
    const float* __restrict__ e, float* __restrict__ RowMax, float* __restrict__ ColMax)
{
  const int b = blockIdx.z, s = blockIdx.x, ori = blockIdx.y;
  const float* eb = e + (size_t)b*SL*SL;
  const int tid = threadIdx.x, lane = tid&63, w = tid>>6;
  if (ori == 0){
    #pragma unroll 4
    for (int t=0;t<16;t++){
      int i = s*64 + w*16 + t;
      float4 v = ((const float4*)(eb + (size_t)i*SL))[lane];
      float m = fmaxf(fmaxf(v.x,v.y), fmaxf(v.z,v.w));
      m=fmaxf(m,__shfl_xor(m,1));  m=fmaxf(m,__shfl_xor(m,2));
      m=fmaxf(m,__shfl_xor(m,4));  m=fmaxf(m,__shfl_xor(m,8));
      m=fmaxf(m,__shfl_xor(m,16)); m=fmaxf(m,__shfl_xor(m,32));
      if (lane==0) RowMax[b*SL+i] = m;
    }
  } else {
    __shared__ float Part[4][64];
    const int j = s*64 + lane;
    float m = -INFINITY;
    for (int i=w; i<SL; i+=4) m = fmaxf(m, eb[(size_t)i*SL + j]);
    Part[w][lane] = m;
    __syncthreads();
    if (w==0)
      ColMax[b*SL+j] = fmaxf(fmaxf(Part[0][lane],Part[1][lane]),
                             fmaxf(Part[2][lane],Part[3][lane]));
  }
}

// ---------- P weights, normalized + masked + ROW-ZEROED ----------
// side0: Pb[i][j] = [i<l1][j<l2] exp(e[i][j]-ColMax[i]) / sum_j(...)
// side1: Pa[j][i] = [j<l2][i<l1] exp(e[i][j]-RowMax[j]) / sum_i(...)
__global__ __launch_bounds__(256) void pwrite_k(
    const float* __restrict__ e, const float* __restrict__ RowMax, const float* __restrict__ ColMax,
    const int* __restrict__ len1, const int* __restrict__ len2,
    short* __restrict__ Pa, short* __restrict__ Pb)
{
  const int b = blockIdx.z, s = blockIdx.x, ori = blockIdx.y;
  const float* eb = e + (size_t)b*SL*SL;
  const int tid = threadIdx.x, lane = tid&63, w = tid>>6;
  if (ori == 0){
    const int l1 = len1[b], l2 = len2[b];
    for (int t=0;t<16;t++){
      int i = s*64 + w*16 + t;
      float cm = ColMax[b*SL+i];
      float4 v = ((const float4*)(eb + (size_t)i*SL))[lane];
      int c0 = lane*4;
      float e0 = (c0+0<l2) ? __expf(fminf(v.x-cm,85.f)) : 0.f;
      float e1 = (c0+1<l2) ? __expf(fminf(v.y-cm,85.f)) : 0.f;
      float e2 = (c0+2<l2) ? __expf(fminf(v.z-cm,85.f)) : 0.f;
      float e3 = (c0+3<l2) ? __expf(fminf(v.w-cm,85.f)) : 0.f;
      float ss = e0+e1+e2+e3;
      ss+=__shfl_xor(ss,1); ss+=__shfl_xor(ss,2); ss+=__shfl_xor(ss,4);
      ss+=__shfl_xor(ss,8); ss+=__shfl_xor(ss,16); ss+=__shfl_xor(ss,32);
      float inv = (ss>0.f && i<l1) ? 1.f/ss : 0.f;   // i>=l1: zero row (mask1 on betas)
      short4v o; o[0]=f2b(e0*inv); o[1]=f2b(e1*inv); o[2]=f2b(e2*inv); o[3]=f2b(e3*inv);
      ((short4v*)(Pb + (size_t)b*SL*SL + (size_t)i*SL))[lane] = o;
    }
  } else {
    __shared__ float Part[4][64];
    __shared__ float SaInv[64];
    __shared__ float RmS[64];
    __shared__ float Tile[64][65];
    const int l1 = len1[b], l2 = len2[b];
    const int j0 = s*64;
    if (tid < 64) RmS[tid] = RowMax[b*SL + j0 + tid];
    __syncthreads();
    {
      float sum = 0.f;
      for (int i=w; i<SL; i+=4)
        if (i < l1) sum += __expf(fminf(eb[(size_t)i*SL + j0 + lane] - RmS[lane], 85.f));
      Part[w][lane] = sum;
    }
    __syncthreads();
    if (w==0){
      float s_ = Part[0][lane]+Part[1][lane]+Part[2][lane]+Part[3][lane];
      SaInv[lane] = (s_>0.f && (j0+lane)<l2) ? 1.f/s_ : 0.f;  // j>=l2: zero row (mask2 on alphas)
    }
    __syncthreads();
    for (int ti=0; ti<4; ti++){
      const int i0 = ti*64;
      #pragma unroll 4
      for (int it=0; it<16; it++){
        int il = it*4 + w;
        int i = i0 + il;
        float v = eb[(size_t)i*SL + j0 + lane];
        float p = (i<l1) ? __expf(fminf(v - RmS[lane],85.f))*SaInv[lane] : 0.f;
        Tile[il][lane] = p;
      }
      __syncthreads();
      {
        int jl = tid>>2, q = tid&3;
        short8 o1, o2;
        #pragma unroll
        for (int u=0;u<8;u++){
          o1[u] = f2b(Tile[q*16+u][jl]);
          o2[u] = f2b(Tile[q*16+8+u][jl]);
        }
        short* dst = Pa + (size_t)b*SL*SL + (size_t)(j0+jl)*SL + i0 + q*16;
        *(short8*)dst = o1;
        *(short8*)(dst+8) = o2;
      }
      __syncthreads();
    }
  }
}

// ---------- ggemm: Gt[n][k] = sum_d embb[idx[k]][d] * W1cb[n][d], stored transposed ----------
// side0: s1 -> G1t ; side1: s2 -> G2t.  grid (8*nbc)
__global__ __launch_bounds__(256) void ggemm(
    const short* __restrict__ embb, const int* __restrict__ s1c, const int* __restrict__ s2c,
    const short* __restrict__ W1bt, short* __restrict__ G1t, short* __restrict__ G2t, int nbc)
{
  __shared__ __align__(16) short As[64*PAD];
  __shared__ __align__(16) short Bs[208*PAD];
  __shared__ __align__(16) short Ts2[208*64];
  __shared__ int IdxS[64];
  const int tid=threadIdx.x, lane=tid&63, w=tid>>6, quad=lane>>4, ln=lane&15;
  const int spp = 4*nbc;
  const int side = (blockIdx.x >= spp) ? 1 : 0;
  int lin = blockIdx.x - side*spp;
  int b, rb;
  if (nbc >= 8){ int sup=lin>>5, rem=lin&31; rb=rem>>3; b=sup*8+(rem&7); }
  else { b = lin>>2; rb = lin&3; }
  const int* idx = side ? s2c : s1c;
  short* Gt = (side ? G2t : G1t) + (size_t)b*GSTR;
  const int krow0 = rb*64;
  if (tid < 64) IdxS[tid] = idx[b*SL + krow0 + tid];
  __syncthreads();
  f32x4 acc[13];
  #pragma unroll
  for (int t=0;t<13;t++) acc[t]=(f32x4){0.f,0.f,0.f,0.f};
  const int r_ = tid>>2, c_ = tid&3;
  for (int ks=0; ks<10; ks++){
    const int k0 = ks*32;
    *(short8*)&As[r_*PAD + c_*8] = *(const short8*)&embb[(size_t)IdxS[r_]*EP + k0 + c_*8];
    #pragma unroll
    for (int it=0; it<4; it++){
      int p = it*256+tid, n = p>>2, cc = p&3;
      if (n < 208)
        *(short8*)&Bs[n*PAD + cc*8] = *(const short8*)&W1bt[(size_t)n*EP + k0 + cc*8];
    }
    __syncthreads();
    short8 a = *(const short8*)&As[(w*16+ln)*PAD + quad*8];
    #pragma unroll
    for (int t=0;t<13;t++){
      short8 bb = *(const short8*)&Bs[(t*16+ln)*PAD + quad*8];
      acc[t] = __builtin_amdgcn_mfma_f32_16x16x32_bf16(a, bb, acc[t], 0,0,0);
    }
    __syncthreads();
  }
  // epilogue: XOR-swizzled LDS transpose (octet o of row n stored at o^(n&7)), no bias/relu
  #pragma unroll
  for (int t=0;t<13;t++){
    int n = t*16+ln;
    #pragma unroll
    for (int r=0;r<4;r++){
      int kl = w*16+quad*4+r;
      int po = ((kl>>3) ^ (n&7));
      Ts2[n*64 + po*8 + (kl&7)] = f2b(acc[t][r]);
    }
  }
  __syncthreads();
  #pragma unroll
  for (int it=0; it<7; it++){
    int p = it*256+tid, n = p>>3, oct = p&7;
    if (n < 208){
      short8 v = *(const short8*)&Ts2[n*64 + (oct^(n&7))*8];
      *(short8*)&Gt[(size_t)n*SL + krow0 + oct*8] = v;
    }
  }
}

// ---------- compare MLP: layer1 = emb@W1cTop (K=320) + P@Gt (K=256), then layer2 + masked sum ----------
// side0: rows s1, P=Pb, G=G2t, len=len1, V=v1 ; side1: rows s2, P=Pa, G=G1t, len=len2, V=v2
__global__ __launch_bounds__(256) void mlp2c(
    const short* __restrict__ embb,
    const int* __restrict__ s1c, const int* __restrict__ s2c,
    const short* __restrict__ Pb, const short* __restrict__ Pa,
    const short* __restrict__ G2t, const short* __restrict__ G1t,
    const short* __restrict__ W1tT, const float* __restrict__ b1,
    const short* __restrict__ W2t, const float* __restrict__ b2,
    const int* __restrict__ len1, const int* __restrict__ len2,
    float* __restrict__ v1, float* __restrict__ v2, int nbc)
{
  __shared__ __align__(16) short As[64*PAD];
  __shared__ __align__(16) short Bs[208*PAD];
  __shared__ __align__(16) short Ts[64*TSP];
  __shared__ int IdxS[64];
  const int tid=threadIdx.x, lane=tid&63, w=tid>>6, quad=lane>>4, ln=lane&15;
  const int spp = 4*nbc;
  const int side = (blockIdx.x >= spp) ? 1 : 0;
  int lin = blockIdx.x - side*spp;
  int b, rb;
  if (nbc >= 8){ int sup=lin>>5, rem=lin&31; rb=rem>>3; b=sup*8+(rem&7); }
  else { b = lin>>2; rb = lin&3; }
  const int prow0 = rb*64;
  const int* idx = side ? s2c : s1c;
  const short* P = (side ? Pa : Pb) + (size_t)b*SL*SL;
  const short* Gt = (side ? G1t : G2t) + (size_t)b*GSTR;
  const int* lenArr = side ? len2 : len1;
  float* V = side ? v2 : v1;
  if (tid < 64) IdxS[tid] = idx[b*SL + prow0 + tid];
  if (tid < 128){ int r=tid>>1, c=tid&1;
    short8 z = {0,0,0,0,0,0,0,0};
    *(short8*)&Ts[r*TSP + 208 + c*8] = z; }
  __syncthreads();

  f32x4 acc[13];
  #pragma unroll
  for (int t=0;t<13;t++) acc[t]=(f32x4){0.f,0.f,0.f,0.f};
  const int r_ = tid>>2, c_ = tid&3;

  // ---- layer 1 phase A: e-part, K=320 ----
  for (int ks=0; ks<10; ks++){
    const int k0 = ks*32;
    *(short8*)&As[r_*PAD + c_*8] = *(const short8*)&embb[(size_t)IdxS[r_]*EP + k0 + c_*8];
    #pragma unroll
    for (int it=0; it<4; it++){
      int p = it*256+tid, n = p>>2, cc = p&3;
      if (n < 208)
        *(short8*)&Bs[n*PAD + cc*8] = *(const short8*)&W1tT[(size_t)n*EP + k0 + cc*8];
    }
    __syncthreads();
    short8 a = *(const short8*)&As[(w*16+ln)*PAD + quad*8];
    #pragma unroll
    for (int t=0;t<13;t++){
      short8 bb = *(const short8*)&Bs[(t*16+ln)*PAD + quad*8];
      acc[t] = __builtin_amdgcn_mfma_f32_16x16x32_bf16(a, bb, acc[t], 0,0,0);
    }
    __syncthreads();
  }
  // ---- layer 1 phase B: P-part, K=256 (continue accumulation) ----
  for (int ks=0; ks<8; ks++){
    const int k0 = ks*32;
    *(short8*)&As[r_*PAD + c_*8] = *(const short8*)&P[(size_t)(prow0+r_)*SL + k0 + c_*8];
    #pragma unroll
    for (int it=0; it<4; it++){
      int p = it*256+tid, n = p>>2, cc = p&3;
      if (n < 208)
        *(short8*)&Bs[n*PAD + cc*8] = *(const short8*)&Gt[(size_t)n*SL + k0 + cc*8];
    }
    __syncthreads();
    short8 a = *(const short8*)&As[(w*16+ln)*PAD + quad*8];
    #pragma unroll
    for (int t=0;t<13;t++){
      short8 bb = *(const short8*)&Bs[(t*16+ln)*PAD + quad*8];
      acc[t] = __builtin_amdgcn_mfma_f32_16x16x32_bf16(a, bb, acc[t], 0,0,0);
    }
    __syncthreads();
  }
  // bias + relu -> Ts
  #pragma unroll
  for (int t=0;t<13;t++){
    int col = t*16+ln;
    float bv = (col<HD) ? b1[col] : 0.f;
    #pragma unroll
    for (int r=0;r<4;r++){
      int rl = w*16+quad*4+r;
      float v = (col<HD) ? fmaxf(acc[t][r]+bv, 0.f) : 0.f;
      Ts[rl*TSP + col] = f2b(v);
    }
    acc[t]=(f32x4){0.f,0.f,0.f,0.f};
  }
  // ---- layer 2 (K=224) ----
  for (int ks=0; ks<7; ks++){
    const int k0 = ks*32;
    #pragma unroll
    for (int it=0; it<4; it++){
      int p = it*256+tid, n = p>>2, cc = p&3;
      if (n < 208)
        *(short8*)&Bs[n*PAD + cc*8] = *(const short8*)&W2t[(size_t)n*HP + k0 + cc*8];
    }
    __syncthreads();
    short8 a = *(const short8*)&Ts[(w*16+ln)*TSP + k0 + quad*8];
    #pragma unroll
    for (int t=0;t<13;t++){
      short8 bb = *(const short8*)&Bs[(t*16+ln)*PAD + quad*8];
      acc[t] = __builtin_amdgcn_mfma_f32_16x16x32_bf16(a, bb, acc[t], 0,0,0);
    }
    __syncthreads();
  }
  // masked row-sum epilogue
  {
    const int lenv = lenArr[b];
    const int posBase = prow0 + w*16 + quad*4;
    #pragma unroll
    for (int t=0;t<13;t++){
      int col = t*16+ln;
      float bv = (col<HD) ? b2[col] : 0.f;
      float s = 0.f;
      #pragma unroll
      for (int r=0;r<4;r++){
        float v = fmaxf(acc[t][r]+bv, 0.f);
        if (posBase + r < lenv) s += v;
      }
      s += __shfl_xor(s,16);
      s += __shfl_xor(s,32);
      if (quad==0 && col<HD) atomicAdd(&V[b*HD+col], s);
    }
  }
}

// ---------- aggregate ----------
__global__ __launch_bounds__(256) void aggregate(
    const float* __restrict__ v1, const float* __restrict__ v2,
    const float* __restrict__ W1g, const float* __restrict__ b1g,
    const float* __restrict__ W2g, const float* __restrict__ b2g,
    float* __restrict__ out)
{
  __shared__ float z[2*HD];
  __shared__ float a[HD];
  const int b = blockIdx.x, t = threadIdx.x;
  if (t < HD){ z[t] = v1[b*HD+t]; z[HD+t] = v2[b*HD+t]; }
  __syncthreads();
  if (t < HD){
    float acc = b1g[t];
    for (int k=0;k<2*HD;k++) acc += z[k]*W1g[(size_t)k*HD+t];
    a[t] = fmaxf(acc, 0.f);
  }
  __syncthreads();
  if (t < 2){
    float acc = b2g[t];
    for (int k=0;k<HD;k++) acc += a[k]*W2g[k*2+t];
    out[b*2+t] = acc;
  }
}

extern "C" void kernel_launch(void* const* d_in, const int* in_sizes, int n_in,
                              void* d_out, int out_size, void* d_ws, size_t ws_size,
                              hipStream_t stream) {
  const float* emb = (const float*)d_in[0];
  const float* W1a = (const float*)d_in[1];  const float* b1a = (const float*)d_in[2];
  const float* W2a = (const float*)d_in[3];  const float* b2a = (const float*)d_in[4];
  const float* W1c = (const float*)d_in[5];  const float* b1c = (const float*)d_in[6];
  const float* W2c = (const float*)d_in[7];  const float* b2c = (const float*)d_in[8];
  const float* W1g = (const float*)d_in[9];  const float* b1g = (const float*)d_in[10];
  const float* W2g = (const float*)d_in[11]; const float* b2g = (const float*)d_in[12];
  const int* s1 = (const int*)d_in[13];
  const int* s2 = (const int*)d_in[14];
  const int* len1 = (const int*)d_in[15];
  const int* len2 = (const int*)d_in[16];
  float* out = (float*)d_out;
  char* W = (char*)d_ws;

  // ---- fixed region ----
  float* v1    = (float*)(W);                      // 409,600
  float* v2    = (float*)(W + 409600);             // 409,600
  short* embb  = (short*)(W + 819200);             // 32,000,000
  short* W1at  = (short*)(W + 32819200);           // 208*320*2 = 133,120
  short* W2at  = (short*)(W + 32952320);           // 208*224*2 =  93,184
  short* W1ctT = (short*)(W + 33045504);           // top half:  133,120
  short* W1cbT = (short*)(W + 33178624);           // bot half:  133,120
  short* W2ct  = (short*)(W + 33311744);           //  93,184
  char*  C0    = W + 33404928;
  const size_t FIXED = 33404928ull;

  // ---- per-batch chunked region ----
  // h1/h2 114688 ea; e 262144; Pa/Pb 131072 ea; G1t/G2t 106496 ea; Rm/Cm 1024 ea
  const size_t PERB = 968704ull;
  int nbc = NB;
  while (nbc > 1 && FIXED + (size_t)nbc*PERB > ws_size) nbc >>= 1;
  const size_t nb = (size_t)nbc;
  short* h1  = (short*)(C0);
  short* h2  = (short*)(C0 + nb*114688);
  float* e   = (float*)(C0 + nb*229376);
  short* Pa  = (short*)(C0 + nb*491520);
  short* Pb  = (short*)(C0 + nb*622592);
  short* G1t = (short*)(C0 + nb*753664);
  short* G2t = (short*)(C0 + nb*860160);
  float* Rm  = (float*)(C0 + nb*966656);
  float* Cm  = (float*)(C0 + nb*967680);

  const dim3 blk(256);
  hipMemsetAsync(v1, 0, 2ull*NB*HD*sizeof(float), stream);
  conv_emb<<<dim3((50000*EP+255)/256), blk, 0, stream>>>(emb, embb);
  convT_plain<<<dim3((208*EP+255)/256), blk, 0, stream>>>(W1a, W1at, ED, EP);
  convT_plain<<<dim3((208*HP+255)/256), blk, 0, stream>>>(W2a, W2at, HD, HP);
  convT_plain<<<dim3((208*EP+255)/256), blk, 0, stream>>>(W1c, W1ctT, ED, EP);            // rows 0..299
  convT_plain<<<dim3((208*EP+255)/256), blk, 0, stream>>>(W1c + (size_t)ED*HD, W1cbT, ED, EP); // rows 300..599
  convT_plain<<<dim3((208*HP+255)/256), blk, 0, stream>>>(W2c, W2ct, HD, HP);

  const int chunks = NB / nbc;
  for (int c = 0; c < chunks; c++){
    const int b0 = c * nbc;
    const int* s1c = s1 + (size_t)b0*SL;
    const int* s2c = s2 + (size_t)b0*SL;
    const int* l1c = len1 + b0;
    const int* l2c = len2 + b0;

    mlp2<<<dim3(8*nbc), blk, 0, stream>>>(embb, s1c, s2c, W1at, b1a, W2at, b2a, h1, h2);
    scores_gemm<<<dim3(4,4,nbc), blk, 0, stream>>>(h1, h2, e);
    maxes_k<<<dim3(4,2,nbc), blk, 0, stream>>>(e, Rm, Cm);
    pwrite_k<<<dim3(4,2,nbc), blk, 0, stream>>>(e, Rm, Cm, l1c, l2c, Pa, Pb);
    ggemm<<<dim3(8*nbc), blk, 0, stream>>>(embb, s1c, s2c, W1cbT, G1t, G2t, nbc);
    mlp2c<<<dim3(8*nbc), blk, 0, stream>>>(embb, s1c, s2c, Pb, Pa, G2t, G1t,
                                           W1ctT, b1c, W2ct, b2c, l1c, l2c,
                                           v1 + (size_t)b0*HD, v2 + (size_t)b0*HD, nbc);
  }
  aggregate<<<dim3(NB), blk, 0, stream>>>(v1, v2, W1g, b1g, W2g, b2g, out);
}

// Round 8
// 887.829 us; speedup vs baseline: 6.9099x; 1.4655x over previous
//
#include <hip/hip_runtime.h>
#include <hip/hip_bf16.h>

#define DEV static __device__ __forceinline__

typedef short short8 __attribute__((ext_vector_type(8)));
typedef short short4v __attribute__((ext_vector_type(4)));
typedef float f32x4 __attribute__((ext_vector_type(4)));

#define NB 512
#define SL 256
#define ED 300
#define HD 200
#define EP 320   // padded embed stride
#define HP 224   // padded hidden stride
#define TSP 232  // LDS layer-1 output tile stride
#define PAD 40
#define GSTR 53248   // per-(b,side) Gt size in shorts: 208*256

DEV short f2b(float f){ __hip_bfloat16 h = __float2bfloat16(f); short s; __builtin_memcpy(&s,&h,2); return s; }

// ---------- one-time conversions ----------
__global__ __launch_bounds__(256) void conv_emb(const float* __restrict__ src, short* __restrict__ dst){
  size_t g = (size_t)blockIdx.x*256 + threadIdx.x;
  if (g >= (size_t)50000*EP) return;
  int row = (int)(g/EP), k = (int)(g%EP);
  dst[g] = (k<ED) ? f2b(src[(size_t)row*ED + k]) : (short)0;
}
// Wt[n][k] (208 x KP) <- W[k][n] (Kreal x 200), zero padded
__global__ __launch_bounds__(256) void convT_plain(const float* __restrict__ W, short* __restrict__ Wt,
                                                   int Kreal, int KP){
  int g = blockIdx.x*256 + threadIdx.x;
  if (g >= 208*KP) return;
  int n = g/KP, k = g%KP;
  float v = (n<HD && k<Kreal) ? W[(size_t)k*HD + n] : 0.f;
  Wt[g] = f2b(v);
}

// ---------- fused 2-layer attend MLP, both sides, register-prefetch pipeline ----------
__global__ __launch_bounds__(256) void mlp2(
    const short* __restrict__ embb,
    const int* __restrict__ idxA, const int* __restrict__ idxB,
    const short* __restrict__ W1t, const float* __restrict__ b1,
    const short* __restrict__ W2t, const float* __restrict__ b2,
    short* __restrict__ OutA, short* __restrict__ OutB)
{
  __shared__ __align__(16) short U[64*TSP];      // As (first 64*PAD) / Ts union
  __shared__ __align__(16) short Bs[208*PAD];
  __shared__ int IdxS[64];
  const int tid=threadIdx.x, lane=tid&63, w=tid>>6, quad=lane>>4, ln=lane&15;
  const int half = gridDim.x>>1;
  const int side = (blockIdx.x >= half) ? 1 : 0;
  const int row0 = (blockIdx.x - side*half)*64;
  const int* idx = side ? idxB : idxA;
  if (tid < 64) IdxS[tid] = idx[row0+tid];
  __syncthreads();

  f32x4 acc[13];
  #pragma unroll
  for (int t=0;t<13;t++) acc[t]=(f32x4){0.f,0.f,0.f,0.f};
  const int r_ = tid>>2, c_ = tid&3;
  const size_t arow = (size_t)IdxS[r_]*EP;

  short8 aR, bR0, bR1, bR2, bR3;
  aR  = *(const short8*)&embb[arow + c_*8];
  bR0 = *(const short8*)&W1t[(size_t)r_*EP + c_*8];
  bR1 = *(const short8*)&W1t[(size_t)(64+r_)*EP + c_*8];
  bR2 = *(const short8*)&W1t[(size_t)(128+r_)*EP + c_*8];
  if (r_<16) bR3 = *(const short8*)&W1t[(size_t)(192+r_)*EP + c_*8];

  // ---- layer 1 (K=320, 10 steps) ----
  for (int ks=0; ks<10; ks++){
    __syncthreads();
    *(short8*)&U[r_*PAD + c_*8] = aR;
    *(short8*)&Bs[r_*PAD + c_*8] = bR0;
    *(short8*)&Bs[(64+r_)*PAD + c_*8] = bR1;
    *(short8*)&Bs[(128+r_)*PAD + c_*8] = bR2;
    if (r_<16) *(short8*)&Bs[(192+r_)*PAD + c_*8] = bR3;
    __syncthreads();
    if (ks < 9){
      const int k0 = (ks+1)*32;
      aR  = *(const short8*)&embb[arow + k0 + c_*8];
      bR0 = *(const short8*)&W1t[(size_t)r_*EP + k0 + c_*8];
      bR1 = *(const short8*)&W1t[(size_t)(64+r_)*EP + k0 + c_*8];
      bR2 = *(const short8*)&W1t[(size_t)(128+r_)*EP + k0 + c_*8];
      if (r_<16) bR3 = *(const short8*)&W1t[(size_t)(192+r_)*EP + k0 + c_*8];
    }
    short8 a = *(const short8*)&U[(w*16+ln)*PAD + quad*8];
    #pragma unroll
    for (int t=0;t<13;t++){
      short8 bb = *(const short8*)&Bs[(t*16+ln)*PAD + quad*8];
      acc[t] = __builtin_amdgcn_mfma_f32_16x16x32_bf16(a, bb, acc[t], 0,0,0);
    }
  }
  __syncthreads();                       // all As reads done before Ts overwrites U
  // layer-1 epilogue -> Ts (=U, stride TSP) + zero pad
  #pragma unroll
  for (int t=0;t<13;t++){
    int col = t*16+ln;
    float bv = (col<HD) ? b1[col] : 0.f;
    #pragma unroll
    for (int r=0;r<4;r++){
      int rl = w*16+quad*4+r;
      float v = (col<HD) ? fmaxf(acc[t][r]+bv, 0.f) : 0.f;
      U[rl*TSP + col] = f2b(v);
    }
    acc[t]=(f32x4){0.f,0.f,0.f,0.f};
  }
  if (tid < 128){ int r=tid>>1, c=tid&1;
    short8 z = {0,0,0,0,0,0,0,0};
    *(short8*)&U[r*TSP + 208 + c*8] = z; }

  // ---- layer 2 (K=224, 7 steps) ----
  bR0 = *(const short8*)&W2t[(size_t)r_*HP + c_*8];
  bR1 = *(const short8*)&W2t[(size_t)(64+r_)*HP + c_*8];
  bR2 = *(const short8*)&W2t[(size_t)(128+r_)*HP + c_*8];
  if (r_<16) bR3 = *(const short8*)&W2t[(size_t)(192+r_)*HP + c_*8];
  for (int ks=0; ks<7; ks++){
    __syncthreads();
    *(short8*)&Bs[r_*PAD + c_*8] = bR0;
    *(short8*)&Bs[(64+r_)*PAD + c_*8] = bR1;
    *(short8*)&Bs[(128+r_)*PAD + c_*8] = bR2;
    if (r_<16) *(short8*)&Bs[(192+r_)*PAD + c_*8] = bR3;
    __syncthreads();
    if (ks < 6){
      const int k0 = (ks+1)*32;
      bR0 = *(const short8*)&W2t[(size_t)r_*HP + k0 + c_*8];
      bR1 = *(const short8*)&W2t[(size_t)(64+r_)*HP + k0 + c_*8];
      bR2 = *(const short8*)&W2t[(size_t)(128+r_)*HP + k0 + c_*8];
      if (r_<16) bR3 = *(const short8*)&W2t[(size_t)(192+r_)*HP + k0 + c_*8];
    }
    short8 a = *(const short8*)&U[(w*16+ln)*TSP + ks*32 + quad*8];
    #pragma unroll
    for (int t=0;t<13;t++){
      short8 bb = *(const short8*)&Bs[(t*16+ln)*PAD + quad*8];
      acc[t] = __builtin_amdgcn_mfma_f32_16x16x32_bf16(a, bb, acc[t], 0,0,0);
    }
  }
  short* Out = side ? OutB : OutA;
  #pragma unroll
  for (int t=0;t<13;t++){
    int col = t*16+ln;
    float bv = (col<HD) ? b2[col] : 0.f;
    #pragma unroll
    for (int r=0;r<4;r++){
      int rl = w*16+quad*4+r;
      float v = (col<HD) ? fmaxf(acc[t][r]+bv, 0.f) : 0.f;
      Out[(size_t)(row0+rl)*HP + col] = f2b(v);
    }
  }
  if (tid < 128){ int r=tid>>1, c=tid&1;
    short8 z = {0,0,0,0,0,0,0,0};
    *(short8*)&Out[(size_t)(row0+r)*HP + 208 + c*8] = z; }
}

// ---------- scores + fused row/col max (e >= 0 since h >= 0) ----------
__global__ __launch_bounds__(256) void scores_gemm(
    const short* __restrict__ h1, const short* __restrict__ h2, float* __restrict__ e,
    unsigned* __restrict__ RmU, unsigned* __restrict__ CmU)
{
  __shared__ __align__(16) short As[64*PAD];
  __shared__ __align__(16) short Bs[64*PAD];
  const int b = blockIdx.z;
  const int i0 = blockIdx.x*64, j0 = blockIdx.y*64;
  const int tid=threadIdx.x, lane=tid&63, w=tid>>6, quad=lane>>4, ln=lane&15;
  const int r_ = tid>>2, c_ = tid&3;
  f32x4 acc[4];
  #pragma unroll
  for (int t=0;t<4;t++) acc[t]=(f32x4){0.f,0.f,0.f,0.f};
  const short* Arow = &h1[((size_t)b*SL + i0 + r_)*HP + c_*8];
  const short* Brow = &h2[((size_t)b*SL + j0 + r_)*HP + c_*8];
  short8 aR = *(const short8*)Arow;
  short8 bR = *(const short8*)Brow;
  for (int ks=0; ks<7; ks++){
    __syncthreads();
    *(short8*)&As[r_*PAD + c_*8] = aR;
    *(short8*)&Bs[r_*PAD + c_*8] = bR;
    __syncthreads();
    if (ks < 6){
      aR = *(const short8*)(Arow + (ks+1)*32);
      bR = *(const short8*)(Brow + (ks+1)*32);
    }
    short8 a = *(const short8*)&As[(w*16+ln)*PAD + quad*8];
    #pragma unroll
    for (int t=0;t<4;t++){
      short8 bb = *(const short8*)&Bs[(t*16+ln)*PAD + quad*8];
      acc[t] = __builtin_amdgcn_mfma_f32_16x16x32_bf16(a, bb, acc[t], 0,0,0);
    }
  }
  #pragma unroll
  for (int t=0;t<4;t++){
    int j = j0 + t*16 + ln;
    #pragma unroll
    for (int r=0;r<4;r++){
      int i = i0 + w*16 + quad*4 + r;
      e[(size_t)b*SL*SL + (size_t)i*SL + j] = acc[t][r];
    }
  }
  // row maxes (over j): reduce over ln within quad-group
  #pragma unroll
  for (int r=0;r<4;r++){
    float m = fmaxf(fmaxf(acc[0][r],acc[1][r]), fmaxf(acc[2][r],acc[3][r]));
    m=fmaxf(m,__shfl_xor(m,1)); m=fmaxf(m,__shfl_xor(m,2));
    m=fmaxf(m,__shfl_xor(m,4)); m=fmaxf(m,__shfl_xor(m,8));
    if (ln==0) atomicMax(&RmU[b*SL + i0 + w*16 + quad*4 + r], __float_as_uint(m));
  }
  // col maxes (over i): reduce over quad
  #pragma unroll
  for (int t=0;t<4;t++){
    float m = fmaxf(fmaxf(acc[t][0],acc[t][1]), fmaxf(acc[t][2],acc[t][3]));
    m=fmaxf(m,__shfl_xor(m,16)); m=fmaxf(m,__shfl_xor(m,32));
    if (quad==0) atomicMax(&CmU[b*SL + j0 + t*16 + ln], __float_as_uint(m));
  }
}

// ---------- P weights, normalized + masked + row-zeroed ----------
__global__ __launch_bounds__(256) void pwrite_k(
    const float* __restrict__ e, const unsigned* __restrict__ RmU, const unsigned* __restrict__ CmU,
    const int* __restrict__ len1, const int* __restrict__ len2,
    short* __restrict__ Pa, short* __restrict__ Pb)
{
  const int b = blockIdx.z, s = blockIdx.x, ori = blockIdx.y;
  const float* eb = e + (size_t)b*SL*SL;
  const int tid = threadIdx.x, lane = tid&63, w = tid>>6;
  if (ori == 0){
    const int l1 = len1[b], l2 = len2[b];
    for (int t=0;t<16;t++){
      int i = s*64 + w*16 + t;
      float cm = __uint_as_float(CmU[b*SL+i]);
      float4 v = ((const float4*)(eb + (size_t)i*SL))[lane];
      int c0 = lane*4;
      float e0 = (c0+0<l2) ? __expf(fminf(v.x-cm,85.f)) : 0.f;
      float e1 = (c0+1<l2) ? __expf(fminf(v.y-cm,85.f)) : 0.f;
      float e2 = (c0+2<l2) ? __expf(fminf(v.z-cm,85.f)) : 0.f;
      float e3 = (c0+3<l2) ? __expf(fminf(v.w-cm,85.f)) : 0.f;
      float ss = e0+e1+e2+e3;
      ss+=__shfl_xor(ss,1); ss+=__shfl_xor(ss,2); ss+=__shfl_xor(ss,4);
      ss+=__shfl_xor(ss,8); ss+=__shfl_xor(ss,16); ss+=__shfl_xor(ss,32);
      float inv = (ss>0.f && i<l1) ? 1.f/ss : 0.f;   // i>=l1: zero row (mask1 on betas)
      short4v o; o[0]=f2b(e0*inv); o[1]=f2b(e1*inv); o[2]=f2b(e2*inv); o[3]=f2b(e3*inv);
      ((short4v*)(Pb + (size_t)b*SL*SL + (size_t)i*SL))[lane] = o;
    }
  } else {
    __shared__ float Part[4][64];
    __shared__ float SaInv[64];
    __shared__ float RmS[64];
    __shared__ float Tile[64][65];
    const int l1 = len1[b], l2 = len2[b];
    const int j0 = s*64;
    if (tid < 64) RmS[tid] = __uint_as_float(RmU[b*SL + j0 + tid]);
    __syncthreads();
    {
      float sum = 0.f;
      for (int i=w; i<SL; i+=4)
        if (i < l1) sum += __expf(fminf(eb[(size_t)i*SL + j0 + lane] - RmS[lane], 85.f));
      Part[w][lane] = sum;
    }
    __syncthreads();
    if (w==0){
      float s_ = Part[0][lane]+Part[1][lane]+Part[2][lane]+Part[3][lane];
      SaInv[lane] = (s_>0.f && (j0+lane)<l2) ? 1.f/s_ : 0.f;  // j>=l2: zero row (mask2 on alphas)
    }
    __syncthreads();
    for (int ti=0; ti<4; ti++){
      const int i0 = ti*64;
      #pragma unroll 4
      for (int it=0; it<16; it++){
        int il = it*4 + w;
        int i = i0 + il;
        float v = eb[(size_t)i*SL + j0 + lane];
        float p = (i<l1) ? __expf(fminf(v - RmS[lane],85.f))*SaInv[lane] : 0.f;
        Tile[il][lane] = p;
      }
      __syncthreads();
      {
        int jl = tid>>2, q = tid&3;
        short8 o1, o2;
        #pragma unroll
        for (int u=0;u<8;u++){
          o1[u] = f2b(Tile[q*16+u][jl]);
          o2[u] = f2b(Tile[q*16+8+u][jl]);
        }
        short* dst = Pa + (size_t)b*SL*SL + (size_t)(j0+jl)*SL + i0 + q*16;
        *(short8*)dst = o1;
        *(short8*)(dst+8) = o2;
      }
      __syncthreads();
    }
  }
}

// ---------- ggemm: Gt[n][k] = sum_d embb[idx[k]][d] * W1cb[n][d], stored transposed ----------
__global__ __launch_bounds__(256) void ggemm(
    const short* __restrict__ embb, const int* __restrict__ s1c, const int* __restrict__ s2c,
    const short* __restrict__ W1bt, short* __restrict__ G1t, short* __restrict__ G2t, int nbc)
{
  __shared__ __align__(16) short U[208*64];      // As (first 64*PAD) / Ts2 union
  __shared__ __align__(16) short Bs[208*PAD];
  __shared__ int IdxS[64];
  const int tid=threadIdx.x, lane=tid&63, w=tid>>6, quad=lane>>4, ln=lane&15;
  const int spp = 4*nbc;
  const int side = (blockIdx.x >= spp) ? 1 : 0;
  int lin = blockIdx.x - side*spp;
  int b, rb;
  if (nbc >= 8){ int sup=lin>>5, rem=lin&31; rb=rem>>3; b=sup*8+(rem&7); }
  else { b = lin>>2; rb = lin&3; }
  const int* idx = side ? s2c : s1c;
  short* Gt = (side ? G2t : G1t) + (size_t)b*GSTR;
  const int krow0 = rb*64;
  if (tid < 64) IdxS[tid] = idx[b*SL + krow0 + tid];
  __syncthreads();
  f32x4 acc[13];
  #pragma unroll
  for (int t=0;t<13;t++) acc[t]=(f32x4){0.f,0.f,0.f,0.f};
  const int r_ = tid>>2, c_ = tid&3;
  const size_t arow = (size_t)IdxS[r_]*EP;
  short8 aR, bR0, bR1, bR2, bR3;
  aR  = *(const short8*)&embb[arow + c_*8];
  bR0 = *(const short8*)&W1bt[(size_t)r_*EP + c_*8];
  bR1 = *(const short8*)&W1bt[(size_t)(64+r_)*EP + c_*8];
  bR2 = *(const short8*)&W1bt[(size_t)(128+r_)*EP + c_*8];
  if (r_<16) bR3 = *(const short8*)&W1bt[(size_t)(192+r_)*EP + c_*8];
  for (int ks=0; ks<10; ks++){
    __syncthreads();
    *(short8*)&U[r_*PAD + c_*8] = aR;
    *(short8*)&Bs[r_*PAD + c_*8] = bR0;
    *(short8*)&Bs[(64+r_)*PAD + c_*8] = bR1;
    *(short8*)&Bs[(128+r_)*PAD + c_*8] = bR2;
    if (r_<16) *(short8*)&Bs[(192+r_)*PAD + c_*8] = bR3;
    __syncthreads();
    if (ks < 9){
      const int k0 = (ks+1)*32;
      aR  = *(const short8*)&embb[arow + k0 + c_*8];
      bR0 = *(const short8*)&W1bt[(size_t)r_*EP + k0 + c_*8];
      bR1 = *(const short8*)&W1bt[(size_t)(64+r_)*EP + k0 + c_*8];
      bR2 = *(const short8*)&W1bt[(size_t)(128+r_)*EP + k0 + c_*8];
      if (r_<16) bR3 = *(const short8*)&W1bt[(size_t)(192+r_)*EP + k0 + c_*8];
    }
    short8 a = *(const short8*)&U[(w*16+ln)*PAD + quad*8];
    #pragma unroll
    for (int t=0;t<13;t++){
      short8 bb = *(const short8*)&Bs[(t*16+ln)*PAD + quad*8];
      acc[t] = __builtin_amdgcn_mfma_f32_16x16x32_bf16(a, bb, acc[t], 0,0,0);
    }
  }
  __syncthreads();
  // epilogue: XOR-swizzled LDS transpose (octet o of row n stored at o^(n&7)), no bias/relu
  #pragma unroll
  for (int t=0;t<13;t++){
    int n = t*16+ln;
    #pragma unroll
    for (int r=0;r<4;r++){
      int kl = w*16+quad*4+r;
      int po = ((kl>>3) ^ (n&7));
      U[n*64 + po*8 + (kl&7)] = f2b(acc[t][r]);
    }
  }
  __syncthreads();
  #pragma unroll
  for (int it=0; it<7; it++){
    int p = it*256+tid, n = p>>3, oct = p&7;
    if (n < 208){
      short8 v = *(const short8*)&U[n*64 + (oct^(n&7))*8];
      *(short8*)&Gt[(size_t)n*SL + krow0 + oct*8] = v;
    }
  }
}

// ---------- compare MLP: layer1 = emb@W1cTop (K=320) + P@Gt (K=256), then layer2 + masked sum ----------
__global__ __launch_bounds__(256) void mlp2c(
    const short* __restrict__ embb,
    const int* __restrict__ s1c, const int* __restrict__ s2c,
    const short* __restrict__ Pb, const short* __restrict__ Pa,
    const short* __restrict__ G2t, const short* __restrict__ G1t,
    const short* __restrict__ W1tT, const float* __restrict__ b1,
    const short* __restrict__ W2t, const float* __restrict__ b2,
    const int* __restrict__ len1, const int* __restrict__ len2,
    float* __restrict__ v1, float* __restrict__ v2, int nbc)
{
  __shared__ __align__(16) short U[64*TSP];      // As / Ts union
  __shared__ __align__(16) short Bs[208*PAD];
  __shared__ int IdxS[64];
  const int tid=threadIdx.x, lane=tid&63, w=tid>>6, quad=lane>>4, ln=lane&15;
  const int spp = 4*nbc;
  const int side = (blockIdx.x >= spp) ? 1 : 0;
  int lin = blockIdx.x - side*spp;
  int b, rb;
  if (nbc >= 8){ int sup=lin>>5, rem=lin&31; rb=rem>>3; b=sup*8+(rem&7); }
  else { b = lin>>2; rb = lin&3; }
  const int prow0 = rb*64;
  const int* idx = side ? s2c : s1c;
  const short* P = (side ? Pa : Pb) + (size_t)b*SL*SL;
  const short* Gt = (side ? G1t : G2t) + (size_t)b*GSTR;
  const int* lenArr = side ? len2 : len1;
  float* V = side ? v2 : v1;
  if (tid < 64) IdxS[tid] = idx[b*SL + prow0 + tid];
  __syncthreads();

  f32x4 acc[13];
  #pragma unroll
  for (int t=0;t<13;t++) acc[t]=(f32x4){0.f,0.f,0.f,0.f};
  const int r_ = tid>>2, c_ = tid&3;
  const size_t arow = (size_t)IdxS[r_]*EP;

  auto loadA = [&](int ks)->short8 {
    if (ks < 10) return *(const short8*)&embb[arow + ks*32 + c_*8];
    return *(const short8*)&P[(size_t)(prow0+r_)*SL + (ks-10)*32 + c_*8];
  };
  auto loadB = [&](int ks, int n)->short8 {
    if (ks < 10) return *(const short8*)&W1tT[(size_t)n*EP + ks*32 + c_*8];
    return *(const short8*)&Gt[(size_t)n*SL + (ks-10)*32 + c_*8];
  };

  short8 aR, bR0, bR1, bR2, bR3;
  aR  = loadA(0);
  bR0 = loadB(0, r_); bR1 = loadB(0, 64+r_); bR2 = loadB(0, 128+r_);
  if (r_<16) bR3 = loadB(0, 192+r_);

  // ---- layer 1: 18 fused K-steps (10 emb@W1cTop + 8 P@Gt) ----
  for (int ks=0; ks<18; ks++){
    __syncthreads();
    *(short8*)&U[r_*PAD + c_*8] = aR;
    *(short8*)&Bs[r_*PAD + c_*8] = bR0;
    *(short8*)&Bs[(64+r_)*PAD + c_*8] = bR1;
    *(short8*)&Bs[(128+r_)*PAD + c_*8] = bR2;
    if (r_<16) *(short8*)&Bs[(192+r_)*PAD + c_*8] = bR3;
    __syncthreads();
    if (ks < 17){
      aR  = loadA(ks+1);
      bR0 = loadB(ks+1, r_); bR1 = loadB(ks+1, 64+r_); bR2 = loadB(ks+1, 128+r_);
      if (r_<16) bR3 = loadB(ks+1, 192+r_);
    }
    short8 a = *(const short8*)&U[(w*16+ln)*PAD + quad*8];
    #pragma unroll
    for (int t=0;t<13;t++){
      short8 bb = *(const short8*)&Bs[(t*16+ln)*PAD + quad*8];
      acc[t] = __builtin_amdgcn_mfma_f32_16x16x32_bf16(a, bb, acc[t], 0,0,0);
    }
  }
  __syncthreads();
  // bias + relu -> Ts (=U) + zero pad
  #pragma unroll
  for (int t=0;t<13;t++){
    int col = t*16+ln;
    float bv = (col<HD) ? b1[col] : 0.f;
    #pragma unroll
    for (int r=0;r<4;r++){
      int rl = w*16+quad*4+r;
      float v = (col<HD) ? fmaxf(acc[t][r]+bv, 0.f) : 0.f;
      U[rl*TSP + col] = f2b(v);
    }
    acc[t]=(f32x4){0.f,0.f,0.f,0.f};
  }
  if (tid < 128){ int r=tid>>1, c=tid&1;
    short8 z = {0,0,0,0,0,0,0,0};
    *(short8*)&U[r*TSP + 208 + c*8] = z; }

  // ---- layer 2 (K=224, 7 steps) ----
  bR0 = *(const short8*)&W2t[(size_t)r_*HP + c_*8];
  bR1 = *(const short8*)&W2t[(size_t)(64+r_)*HP + c_*8];
  bR2 = *(const short8*)&W2t[(size_t)(128+r_)*HP + c_*8];
  if (r_<16) bR3 = *(const short8*)&W2t[(size_t)(192+r_)*HP + c_*8];
  for (int ks=0; ks<7; ks++){
    __syncthreads();
    *(short8*)&Bs[r_*PAD + c_*8] = bR0;
    *(short8*)&Bs[(64+r_)*PAD + c_*8] = bR1;
    *(short8*)&Bs[(128+r_)*PAD + c_*8] = bR2;
    if (r_<16) *(short8*)&Bs[(192+r_)*PAD + c_*8] = bR3;
    __syncthreads();
    if (ks < 6){
      const int k0 = (ks+1)*32;
      bR0 = *(const short8*)&W2t[(size_t)r_*HP + k0 + c_*8];
      bR1 = *(const short8*)&W2t[(size_t)(64+r_)*HP + k0 + c_*8];
      bR2 = *(const short8*)&W2t[(size_t)(128+r_)*HP + k0 + c_*8];
      if (r_<16) bR3 = *(const short8*)&W2t[(size_t)(192+r_)*HP + k0 + c_*8];
    }
    short8 a = *(const short8*)&U[(w*16+ln)*TSP + ks*32 + quad*8];
    #pragma unroll
    for (int t=0;t<13;t++){
      short8 bb = *(const short8*)&Bs[(t*16+ln)*PAD + quad*8];
      acc[t] = __builtin_amdgcn_mfma_f32_16x16x32_bf16(a, bb, acc[t], 0,0,0);
    }
  }
  // masked row-sum epilogue
  {
    const int lenv = lenArr[b];
    const int posBase = prow0 + w*16 + quad*4;
    #pragma unroll
    for (int t=0;t<13;t++){
      int col = t*16+ln;
      float bv = (col<HD) ? b2[col] : 0.f;
      float s = 0.f;
      #pragma unroll
      for (int r=0;r<4;r++){
        float v = fmaxf(acc[t][r]+bv, 0.f);
        if (posBase + r < lenv) s += v;
      }
      s += __shfl_xor(s,16);
      s += __shfl_xor(s,32);
      if (quad==0 && col<HD) atomicAdd(&V[b*HD+col], s);
    }
  }
}

// ---------- aggregate ----------
__global__ __launch_bounds__(256) void aggregate(
    const float* __restrict__ v1, const float* __restrict__ v2,
    const float* __restrict__ W1g, const float* __restrict__ b1g,
    const float* __restrict__ W2g, const float* __restrict__ b2g,
    float* __restrict__ out)
{
  __shared__ float z[2*HD];
  __shared__ float a[HD];
  const int b = blockIdx.x, t = threadIdx.x;
  if (t < HD){ z[t] = v1[b*HD+t]; z[HD+t] = v2[b*HD+t]; }
  __syncthreads();
  if (t < HD){
    float acc = b1g[t];
    for (int k=0;k<2*HD;k++) acc += z[k]*W1g[(size_t)k*HD+t];
    a[t] = fmaxf(acc, 0.f);
  }
  __syncthreads();
  if (t < 2){
    float acc = b2g[t];
    for (int k=0;k<HD;k++) acc += a[k]*W2g[k*2+t];
    out[b*2+t] = acc;
  }
}

extern "C" void kernel_launch(void* const* d_in, const int* in_sizes, int n_in,
                              void* d_out, int out_size, void* d_ws, size_t ws_size,
                              hipStream_t stream) {
  const float* emb = (const float*)d_in[0];
  const float* W1a = (const float*)d_in[1];  const float* b1a = (const float*)d_in[2];
  const float* W2a = (const float*)d_in[3];  const float* b2a = (const float*)d_in[4];
  const float* W1c = (const float*)d_in[5];  const float* b1c = (const float*)d_in[6];
  const float* W2c = (const float*)d_in[7];  const float* b2c = (const float*)d_in[8];
  const float* W1g = (const float*)d_in[9];  const float* b1g = (const float*)d_in[10];
  const float* W2g = (const float*)d_in[11]; const float* b2g = (const float*)d_in[12];
  const int* s1 = (const int*)d_in[13];
  const int* s2 = (const int*)d_in[14];
  const int* len1 = (const int*)d_in[15];
  const int* len2 = (const int*)d_in[16];
  float* out = (float*)d_out;
  char* W = (char*)d_ws;

  // ---- fixed region ----
  float* v1    = (float*)(W);                      // 409,600
  float* v2    = (float*)(W + 409600);             // 409,600
  short* embb  = (short*)(W + 819200);             // 32,000,000
  short* W1at  = (short*)(W + 32819200);           // 133,120
  short* W2at  = (short*)(W + 32952320);           //  93,184
  short* W1ctT = (short*)(W + 33045504);           // 133,120
  short* W1cbT = (short*)(W + 33178624);           // 133,120
  short* W2ct  = (short*)(W + 33311744);           //  93,184
  char*  C0    = W + 33404928;
  const size_t FIXED = 33404928ull;

  // ---- per-batch chunked region ----
  // h1/h2 114688 ea; e 262144; Pa/Pb 131072 ea; G1t/G2t 106496 ea; Rm/Cm 1024 ea
  const size_t PERB = 968704ull;
  int nbc = NB;
  while (nbc > 1 && FIXED + (size_t)nbc*PERB > ws_size) nbc >>= 1;
  const size_t nb = (size_t)nbc;
  short*    h1  = (short*)(C0);
  short*    h2  = (short*)(C0 + nb*114688);
  float*    e   = (float*)(C0 + nb*229376);
  short*    Pa  = (short*)(C0 + nb*491520);
  short*    Pb  = (short*)(C0 + nb*622592);
  short*    G1t = (short*)(C0 + nb*753664);
  short*    G2t = (short*)(C0 + nb*860160);
  unsigned* Rm  = (unsigned*)(C0 + nb*966656);
  unsigned* Cm  = (unsigned*)(C0 + nb*967680);

  const dim3 blk(256);
  hipMemsetAsync(v1, 0, 2ull*NB*HD*sizeof(float), stream);
  conv_emb<<<dim3((50000*EP+255)/256), blk, 0, stream>>>(emb, embb);
  convT_plain<<<dim3((208*EP+255)/256), blk, 0, stream>>>(W1a, W1at, ED, EP);
  convT_plain<<<dim3((208*HP+255)/256), blk, 0, stream>>>(W2a, W2at, HD, HP);
  convT_plain<<<dim3((208*EP+255)/256), blk, 0, stream>>>(W1c, W1ctT, ED, EP);
  convT_plain<<<dim3((208*EP+255)/256), blk, 0, stream>>>(W1c + (size_t)ED*HD, W1cbT, ED, EP);
  convT_plain<<<dim3((208*HP+255)/256), blk, 0, stream>>>(W2c, W2ct, HD, HP);

  const int chunks = NB / nbc;
  for (int c = 0; c < chunks; c++){
    const int b0 = c * nbc;
    const int* s1c = s1 + (size_t)b0*SL;
    const int* s2c = s2 + (size_t)b0*SL;
    const int* l1c = len1 + b0;
    const int* l2c = len2 + b0;

    hipMemsetAsync(Rm, 0, (size_t)nbc*SL*8, stream);   // Rm + Cm (contiguous), e>=0 so 0 is -inf
    mlp2<<<dim3(8*nbc), blk, 0, stream>>>(embb, s1c, s2c, W1at, b1a, W2at, b2a, h1, h2);
    scores_gemm<<<dim3(4,4,nbc), blk, 0, stream>>>(h1, h2, e, Rm, Cm);
    pwrite_k<<<dim3(4,2,nbc), blk, 0, stream>>>(e, Rm, Cm, l1c, l2c, Pa, Pb);
    ggemm<<<dim3(8*nbc), blk, 0, stream>>>(embb, s1c, s2c, W1cbT, G1t, G2t, nbc);
    mlp2c<<<dim3(8*nbc), blk, 0, stream>>>(embb, s1c, s2c, Pb, Pa, G2t, G1t,
                                           W1ctT, b1c, W2ct, b2c, l1c, l2c,
                                           v1 + (size_t)b0*HD, v2 + (size_t)b0*HD, nbc);
  }
  aggregate<<<dim3(NB), blk, 0, stream>>>(v1, v2, W1g, b1g, W2g, b2g, out);
}